// Round 10
// baseline (3498.793 us; speedup 1.0000x reference)
//
#include <hip/hip_runtime.h>
#include <stdint.h>

// MoleculeDecoder r10: r9 with the h-store write-amplification fixed.
// r9 post-mortem: 2B global_store_short sc0sc1 h-stores caused +247MB HBM
// write amplification (WRITE 430->677MB) — unpack-free reads were a win
// (VALUBusy 8->4.5%) but stores ate it. r10 keeps the blocked hi/lo ring +
// rootless barrier + gh lines + early stores, and pairs combine elements
// (2 adjacent per thread) so h stores are 2x4B dword AGENT_STs again.

typedef unsigned long long u64;
typedef unsigned int u32;
typedef unsigned short ush;
typedef _Float16 f16;
using half8 = __attribute__((ext_vector_type(8))) _Float16;
using f32x4 = __attribute__((ext_vector_type(4))) float;

#define E_ 768
#define V_ 8192
#define T_ 256
#define HP 24576            // 32*768 (one h plane, elements)
#define IH_PLANE (2304*768)
#define OUT_PLANE (8192*768)
#define NBLK 256
#define HS_STEP 49152       // ushorts per ring slot (32*768*2)
#define HS_ROW  1536        // ushorts per batch row (768*2)

#define AGENT_LD(p)    __hip_atomic_load((p), __ATOMIC_RELAXED, __HIP_MEMORY_SCOPE_AGENT)
#define AGENT_ST(p,v)  __hip_atomic_store((p), (v), __ATOMIC_RELAXED, __HIP_MEMORY_SCOPE_AGENT)
#define AGENT_ADD(p,v) __hip_atomic_fetch_add((p), (v), __ATOMIC_RELAXED, __HIP_MEMORY_SCOPE_AGENT)

__device__ __forceinline__ f32x4 mfma16(half8 a, half8 b, f32x4 c){
  return __builtin_amdgcn_mfma_f32_16x16x32_f16(a, b, c, 0, 0, 0);
}
__device__ __forceinline__ void split2(float f, f16& hi, f16& lo){
  f16 h = (f16)f; hi = h; lo = (f16)((f - (float)h) * 4096.0f);
}
__device__ __forceinline__ u32 packh(float f){
  f16 h, l; split2(f, h, l);
  return (u32)__builtin_bit_cast(ush, h) | ((u32)__builtin_bit_cast(ush, l) << 16);
}
__device__ __forceinline__ float unpackh(u32 u){
  f16 h = __builtin_bit_cast(f16, (ush)(u & 0xffffu));
  f16 l = __builtin_bit_cast(f16, (ush)(u >> 16));
  return (float)h + (float)l * (1.0f/4096.0f);
}
__device__ __forceinline__ u64 packkey(float f, int v){
  u32 fb = __float_as_uint(f);
  u32 s  = fb ^ ((u32)((int32_t)fb>>31) | 0x80000000u);
  return ((u64)s<<32) | (u64)(0xFFFFFFFFu - (u32)v);   // ties -> smaller idx wins
}

// ---------------- prep: split weights; h0 (f32 + ring slot 0, blocked layout); zero barrier ----------------
#define NB_CONV 1200
#define NB_H0   96
#define NG_IH   221184      // 2304*768/8
#define NG_ALL  1228800     // (2*2304 + 8192)*768/8

__global__ __launch_bounds__(256) void prep_k(
    const float* __restrict__ W_ih, const float* __restrict__ W_hh, const float* __restrict__ W_out,
    const float* __restrict__ latent, const float* __restrict__ W_lat, const float* __restrict__ b_lat,
    f16* __restrict__ Wih_s, f16* __restrict__ Whh_s, f16* __restrict__ Wout_s,
    float* __restrict__ h_f32, u32* __restrict__ h_seq, unsigned* __restrict__ bar)
{
  int blk = blockIdx.x;
  if (blk < NB_CONV){
    for (int g = blk*256 + threadIdx.x; g < NG_ALL; g += NB_CONV*256){
      const float* src; f16* hi; f16* lo; int off;
      if (g < NG_IH)        { src=W_ih; hi=Wih_s; lo=Wih_s+IH_PLANE; off=g*8; }
      else if (g < 2*NG_IH) { src=W_hh; hi=Whh_s; lo=Whh_s+IH_PLANE; off=(g-NG_IH)*8; }
      else                  { src=W_out; hi=Wout_s; lo=Wout_s+OUT_PLANE; off=(g-2*NG_IH)*8; }
      float4 a = *(const float4*)(src+off);
      float4 b = *(const float4*)(src+off+4);
      float fs[8] = {a.x,a.y,a.z,a.w,b.x,b.y,b.z,b.w};
      half8 vh, vl;
      #pragma unroll
      for (int j=0;j<8;j++){ f16 h,l; split2(fs[j],h,l); vh[j]=h; vl[j]=l; }
      *(half8*)(hi+off) = vh;
      *(half8*)(lo+off) = vl;
    }
  } else {
    if (blk==NB_CONV) bar[threadIdx.x] = 0;        // zero all barrier counters
    int tid = (blk-NB_CONV)*256 + threadIdx.x;     // 0..24575
    int b = tid/768, e = tid - b*768;
    const float4* wr = (const float4*)(W_lat + (size_t)e*768);
    const float4* xr = (const float4*)(latent + (size_t)b*768);
    float s0=0.f,s1=0.f,s2=0.f,s3=0.f;
    for (int k=0;k<192;k++){
      float4 w = wr[k]; float4 x = xr[k];
      s0 += w.x*x.x; s1 += w.y*x.y; s2 += w.z*x.z; s3 += w.w*x.w;
    }
    float acc = b_lat[e] + ((s0+s1)+(s2+s3));
    h_f32[b*768+e] = acc;
    f16 hh, ll; split2(acc, hh, ll);
    ush* hw = (ush*)h_seq + b*HS_ROW + (e>>3)*16 + (e&7);   // slot 0, blocked layout
    hw[0] = __builtin_bit_cast(ush, hh);
    hw[8] = __builtin_bit_cast(ush, ll);
  }
}

// ---------------- gi table: gi_tab[tok][2304] = packed(W_ih @ emb[tok]) ----------------
__global__ __launch_bounds__(512) void gitab_k(
    const float* __restrict__ emb, const f16* __restrict__ Wih_s, u32* __restrict__ gi_tab)
{
  __shared__ float red[3][8][2][64][4];
  const int bid = blockIdx.x, tid = threadIdx.x;
  const int tb = bid>>1, half = bid&1;
  const int w = tid>>6, lane = tid&63, col = lane&15, kg = lane>>4, kc = w;
  half8 ah[2][3], al[2][3];
  #pragma unroll
  for (int m=0;m<2;m++)
    #pragma unroll
    for (int i=0;i<3;i++){
      const float* src = emb + (size_t)(tb*32 + m*16 + col)*768 + kc*96 + i*32 + kg*8;
      float4 x0 = *(const float4*)src, x1 = *(const float4*)(src+4);
      float fs[8] = {x0.x,x0.y,x0.z,x0.w,x1.x,x1.y,x1.z,x1.w};
      half8 vh, vl;
      #pragma unroll
      for (int j=0;j<8;j++){ f16 h,l; split2(fs[j],h,l); vh[j]=h; vl[j]=l; }
      ah[m][i]=vh; al[m][i]=vl;
    }
  for (int g=0; g<24; ++g){
    #pragma unroll
    for (int j=0;j<3;j++){
      const int nt = half*72 + g*3 + j;
      f32x4 a0[2], a1[2];
      #pragma unroll
      for (int m=0;m<2;m++){ a0[m]=f32x4{0,0,0,0}; a1[m]=f32x4{0,0,0,0}; }
      #pragma unroll
      for (int i=0;i<3;i++){
        size_t o = (size_t)(nt*16+col)*768 + kc*96 + i*32 + kg*8;
        half8 bh = *(const half8*)(Wih_s + o);
        half8 bl = *(const half8*)(Wih_s + IH_PLANE + o);
        #pragma unroll
        for (int m=0;m<2;m++){
          a0[m] = mfma16(ah[m][i], bh, a0[m]);
          a1[m] = mfma16(ah[m][i], bl, a1[m]);
          a1[m] = mfma16(al[m][i], bh, a1[m]);
        }
      }
      #pragma unroll
      for (int m=0;m<2;m++){
        f32x4 v;
        #pragma unroll
        for (int r=0;r<4;r++) v[r] = a0[m][r] + a1[m][r]*(1.0f/4096.0f);
        *(f32x4*)&red[j][w][m][lane][0] = v;
      }
    }
    __syncthreads();
    if (w < 6){
      const int j = w>>1, m = w&1;
      f32x4 s = {0,0,0,0};
      #pragma unroll
      for (int ww=0; ww<8; ww++) s += *(const f32x4*)&red[j][ww][m][lane][0];
      const int nt = half*72 + g*3 + j;
      const int tokr = tb*32 + m*16 + kg*4;
      #pragma unroll
      for (int r=0;r<4;r++)
        gi_tab[(size_t)(tokr+r)*2304 + nt*16 + col] = packh(s[r]);
    }
    __syncthreads();
  }
}

// ---------------- grid barrier v4: 16 groups x 16 blocks, NO root hop ----------------
__device__ __forceinline__ void gridbar(unsigned* bar, unsigned target){
  __syncthreads();   // drains each wave's vmem ops (sc1 stores now globally visible)
  if (threadIdx.x < 64){
    if (threadIdx.x == 0) AGENT_ADD(&bar[(blockIdx.x & 15)*16], 1u);
    const u32 goal = 16u*target;
    const int lane = threadIdx.x;
    for(;;){
      u32 v = (lane < 16) ? AGENT_LD(&bar[lane*16]) : goal;
      if (__all(v >= goal)) break;
      __builtin_amdgcn_s_sleep(1);
    }
  }
  __syncthreads();
}

// ---------------- persistent decode kernel (cooperative, 256 x 512) ----------------
__global__ __launch_bounds__(512, 2) void decode_k(
    const f16* __restrict__ Wout_s, const f16* __restrict__ Whh_s, const u32* __restrict__ gi_tab,
    float* __restrict__ gh_buf, const float* __restrict__ h_f32, u32* __restrict__ h_seq,
    u64* __restrict__ candbufT, const float* __restrict__ b_ih, const float* __restrict__ b_hh,
    const float* __restrict__ b_out, float* __restrict__ out, unsigned* __restrict__ bar)
{
  __shared__ float red[3][8][2][64][4];   // 48 KB
  __shared__ u64 amkey[32];
  const int bid = blockIdx.x, tid = threadIdx.x;
  const int w = tid>>6, lane = tid&63, col = lane&15, kg = lane>>4, kc = w;

  // One-time L2/L1 invalidate: kill any stale (poison) lines before cached h reads.
  __builtin_amdgcn_fence(__ATOMIC_ACQUIRE, "agent");
  __syncthreads();

  // ---- persistent B fragments (held in VGPRs for the whole kernel) ----
  const f16* srcH[3] = {Wout_s, Wout_s, (bid<144)? Whh_s : Wout_s};
  const f16* srcL[3] = {Wout_s+OUT_PLANE, Wout_s+OUT_PLANE,
                        (bid<144)? Whh_s+IH_PLANE : Wout_s+OUT_PLANE};
  const int  rowb[3] = {bid*16, 4096+bid*16, (bid<144)? bid*16 : 0};
  half8 bf_h[3][3], bf_l[3][3];
  #pragma unroll
  for (int s=0;s<3;s++)
    #pragma unroll
    for (int i=0;i<3;i++){
      size_t o = (size_t)(rowb[s]+col)*768 + kc*96 + i*32 + kg*8;
      bf_h[s][i] = *(const half8*)(srcH[s] + o);
      bf_l[s][i] = *(const half8*)(srcL[s] + o);
    }
  float bo_reg[2];
  bo_reg[0] = b_out[bid*16 + col];
  bo_reg[1] = b_out[4096 + bid*16 + col];

  // combine-role hoists: blocks 0..47, threads 0..255 own element PAIR (cb, ce..ce+1)
  const bool is_cmb = (bid < 48) && (tid < 256);
  int cb = 0, ce = 0; float hr0 = 0.f, hr1 = 0.f;
  float bi0r=0,bi0z=0,bi0n=0, bi1r=0,bi1z=0,bi1n=0;
  float bh0r=0,bh0z=0,bh0n=0, bh1r=0,bh1z=0,bh1n=0;
  if (is_cmb){
    int p = bid*256 + tid;          // pair index, elements 2p, 2p+1
    int e0 = 2*p;
    cb = e0/768; ce = e0 - cb*768;  // ce even; 768%128==0 => cb wave-uniform
    hr0 = h_f32[cb*768 + ce];  hr1 = h_f32[cb*768 + ce + 1];
    bi0r=b_ih[ce];      bi0z=b_ih[768+ce];      bi0n=b_ih[1536+ce];
    bi1r=b_ih[ce+1];    bi1z=b_ih[768+ce+1];    bi1n=b_ih[1536+ce+1];
    bh0r=b_hh[ce];      bh0z=b_hh[768+ce];      bh0n=b_hh[1536+ce];
    bh1r=b_hh[ce+1];    bh1z=b_hh[768+ce+1];    bh1n=b_hh[1536+ce+1];
  }
  // gh writer constants (blocks 0..143, slot-2 reducer wave)
  const int gr2 = bid*16 + col;
  const int gg2 = gr2/768, ge2 = gr2 - (gr2/768)*768;

  unsigned bt = 0;
  for (int t=0; t<=256; ++t){
    // =================== phase A ===================
    if (tid < 32) amkey[tid] = 0;
    // A-frags: DIRECT half8 cached loads from this step's ring slot
    const ush* h16 = (const ush*)h_seq + (size_t)t*HS_STEP;
    half8 ah[2][3], al[2][3];
    #pragma unroll
    for (int m=0;m<2;m++)
      #pragma unroll
      for (int i=0;i<3;i++){
        const ush* hp = h16 + (m*16+col)*HS_ROW + (kc*12+i*4+kg)*16;
        ah[m][i] = *(const half8*)(hp);
        al[m][i] = *(const half8*)(hp+8);
      }
    #pragma unroll
    for (int s=0;s<3;s++){
      f32x4 a0[2], a1[2];
      #pragma unroll
      for (int m=0;m<2;m++){ a0[m]=f32x4{0,0,0,0}; a1[m]=f32x4{0,0,0,0}; }
      #pragma unroll
      for (int i=0;i<3;i++)
        #pragma unroll
        for (int m=0;m<2;m++){
          a0[m] = mfma16(ah[m][i], bf_h[s][i], a0[m]);
          a1[m] = mfma16(ah[m][i], bf_l[s][i], a1[m]);
          a1[m] = mfma16(al[m][i], bf_h[s][i], a1[m]);
        }
      #pragma unroll
      for (int m=0;m<2;m++){
        f32x4 v;
        #pragma unroll
        for (int r=0;r<4;r++) v[r] = a0[m][r] + a1[m][r]*(1.0f/4096.0f);
        *(f32x4*)&red[s][w][m][lane][0] = v;
      }
    }
    __syncthreads();
    float sv[2][4];                       // deferred logit stores (cross-barrier)
    bool have_out = false;
    if (w < 3){
      const int s = w;
      float vm[2][4];
      #pragma unroll
      for (int m=0;m<2;m++){
        f32x4 sum = {0,0,0,0};
        #pragma unroll
        for (int ww=0; ww<8; ww++) sum += *(const f32x4*)&red[s][ww][m][lane][0];
        #pragma unroll
        for (int r=0;r<4;r++) vm[m][r] = sum[r];
      }
      if (s < 2){
        if (t >= 1){
          have_out = true;
          const int v = s*4096 + bid*16 + col;
          const float bo = bo_reg[s];
          #pragma unroll
          for (int m=0;m<2;m++)
            #pragma unroll
            for (int r=0;r<4;r++){
              const int b = m*16 + kg*4 + r;
              const float p = vm[m][r] + bo;
              sv[m][r] = p;
              u64 key = packkey(p, v);
              #pragma unroll
              for (int off=1; off<16; off<<=1){
                u64 o = __shfl_xor((unsigned long long)key, off);
                if (o > key) key = o;
              }
              if (col == 0) atomicMax(&amkey[b], key);
            }
        }
      } else if (bid < 144){
        // gh -> [b][e][4] f32 (combine reads one line per (b,e))
        #pragma unroll
        for (int m=0;m<2;m++)
          #pragma unroll
          for (int r=0;r<4;r++)
            AGENT_ST(&gh_buf[((size_t)(m*16+kg*4+r)*768 + ge2)*4 + gg2], vm[m][r]);
      }
    }
    __syncthreads();                      // amkey final
    if (t >= 1 && tid < 32) AGENT_ST(&candbufT[(size_t)tid*256 + bid], amkey[tid]);
    if (t == 256){                        // last step: store logits, done
      if (have_out){
        const int v = w*4096 + bid*16 + col;
        #pragma unroll
        for (int m=0;m<2;m++)
          #pragma unroll
          for (int r=0;r<4;r++)
            out[(size_t)(m*16+kg*4+r)*((size_t)T_*V_) + (size_t)(t-1)*V_ + v] = sv[m][r];
      }
      break;
    }
    gridbar(bar, ++bt);
    // =================== out stores + phase B ===================
    if (bid >= 48){
      if (have_out){
        const int v = w*4096 + bid*16 + col;
        #pragma unroll
        for (int m=0;m<2;m++)
          #pragma unroll
          for (int r=0;r<4;r++)
            out[(size_t)(m*16+kg*4+r)*((size_t)T_*V_) + (size_t)(t-1)*V_ + v] = sv[m][r];
      }
    } else {
      // early issue (independent of tok): gh lines for both elements
      float g0r=0,g0z=0,g0n=0, g1r=0,g1z=0,g1n=0;
      if (is_cmb){
        const float* hb4 = gh_buf + ((size_t)cb*768 + ce)*4;
        g0r = AGENT_LD(hb4 + 0); g0z = AGENT_LD(hb4 + 1); g0n = AGENT_LD(hb4 + 2);
        g1r = AGENT_LD(hb4 + 4); g1z = AGENT_LD(hb4 + 5); g1n = AGENT_LD(hb4 + 6);
      }
      if (have_out){                      // overlap HBM acks with the gather
        const int v = w*4096 + bid*16 + col;
        #pragma unroll
        for (int m=0;m<2;m++)
          #pragma unroll
          for (int r=0;r<4;r++)
            out[(size_t)(m*16+kg*4+r)*((size_t)T_*V_) + (size_t)(t-1)*V_ + v] = sv[m][r];
      }
      int tok = 1;
      if (t > 0 && tid < 256){
        u64 k = 0;
        #pragma unroll
        for (int j=0;j<4;j++){
          u64 c = AGENT_LD(&candbufT[(size_t)cb*256 + lane + 64*j]);
          if (c > k) k = c;
        }
        #pragma unroll
        for (int off=1; off<64; off<<=1){
          u64 o = __shfl_xor((unsigned long long)k, off);
          if (o > k) k = o;
        }
        tok = (int)(0xFFFFFFFFu - (unsigned)(k & 0xFFFFFFFFull));
      }
      if (is_cmb){
        const u32* gp = gi_tab + (size_t)tok*2304 + ce;   // plain cached (read-only)
        u64 gR = *(const u64*)(gp);
        u64 gZ = *(const u64*)(gp + 768);
        u64 gN = *(const u64*)(gp + 1536);
        const float gi0r = unpackh((u32)gR)      + bi0r;
        const float gi1r = unpackh((u32)(gR>>32))+ bi1r;
        const float gi0z = unpackh((u32)gZ)      + bi0z;
        const float gi1z = unpackh((u32)(gZ>>32))+ bi1z;
        const float gi0n = unpackh((u32)gN)      + bi0n;
        const float gi1n = unpackh((u32)(gN>>32))+ bi1n;
        const float r0 = 1.0f/(1.0f+expf(-(gi0r + g0r + bh0r)));
        const float z0 = 1.0f/(1.0f+expf(-(gi0z + g0z + bh0z)));
        const float n0 = tanhf(gi0n + r0*(g0n + bh0n));
        hr0 = (1.0f-z0)*n0 + z0*hr0;
        const float r1 = 1.0f/(1.0f+expf(-(gi1r + g1r + bh1r)));
        const float z1 = 1.0f/(1.0f+expf(-(gi1z + g1z + bh1z)));
        const float n1 = tanhf(gi1n + r1*(g1n + bh1n));
        hr1 = (1.0f-z1)*n1 + z1*hr1;
        // h store: blocked hi/lo layout, 2x4B dword AGENT_ST (pair-packed)
        f16 h0,l0,h1,l1; split2(hr0,h0,l0); split2(hr1,h1,l1);
        u32 wHi = (u32)__builtin_bit_cast(ush,h0) | ((u32)__builtin_bit_cast(ush,h1)<<16);
        u32 wLo = (u32)__builtin_bit_cast(ush,l0) | ((u32)__builtin_bit_cast(ush,l1)<<16);
        u32* hw = (u32*)((ush*)h_seq + (size_t)(t+1)*HS_STEP + cb*HS_ROW + (ce>>3)*16 + (ce&7));
        AGENT_ST(hw,     wHi);
        AGENT_ST(hw + 4, wLo);            // +8 ushorts = +4 u32
      }
    }
    gridbar(bar, ++bt);
  }
}

// ---------------- host ----------------
extern "C" void kernel_launch(void* const* d_in, const int* in_sizes, int n_in,
                              void* d_out, int out_size, void* d_ws, size_t ws_size,
                              hipStream_t stream){
  const float* latent = (const float*)d_in[0];
  const float* W_lat  = (const float*)d_in[1];
  const float* b_lat  = (const float*)d_in[2];
  const float* emb    = (const float*)d_in[3];
  const float* W_ih   = (const float*)d_in[4];
  const float* W_hh   = (const float*)d_in[5];
  const float* b_ih   = (const float*)d_in[6];
  const float* b_hh   = (const float*)d_in[7];
  const float* W_out  = (const float*)d_in[8];
  const float* b_out  = (const float*)d_in[9];
  float* out = (float*)d_out;
  (void)in_sizes; (void)n_in; (void)out_size; (void)ws_size;

  char* ws = (char*)d_ws;
  size_t off = 0;
  auto carve = [&](size_t bytes)->char*{
    char* p = ws + off; off += (bytes + 255) & ~(size_t)255; return p;
  };
  f16*      Wih_s  = (f16*)     carve((size_t)2*IH_PLANE*2);    //  7.08 MB
  f16*      Whh_s  = (f16*)     carve((size_t)2*IH_PLANE*2);    //  7.08 MB
  f16*      Wout_s = (f16*)     carve((size_t)2*OUT_PLANE*2);   // 25.17 MB
  u32*      gi_tab = (u32*)     carve((size_t)8192*2304*4);     // 37.75 MB (packed)
  float*    gh_buf = (float*)   carve((size_t)32*768*4*4);      //  0.39 MB ([b][e][4])
  float*    h_f32  = (float*)   carve((size_t)HP*4);            //  0.10 MB
  u32*      h_seq  = (u32*)     carve((size_t)257*HP*4);        // 25.26 MB ring (blocked hi/lo)
  u64*      candbufT=(u64*)     carve((size_t)32*256*8);        //  0.07 MB
  unsigned* bar    = (unsigned*)carve(2048);
  // total ~103 MB of d_ws

  hipLaunchKernelGGL(prep_k, dim3(NB_CONV+NB_H0), dim3(256), 0, stream,
                     W_ih, W_hh, W_out, latent, W_lat, b_lat,
                     Wih_s, Whh_s, Wout_s, h_f32, h_seq, bar);
  hipLaunchKernelGGL(gitab_k, dim3(512), dim3(512), 0, stream, emb, Wih_s, gi_tab);

  void* kargs[] = {
    (void*)&Wout_s, (void*)&Whh_s, (void*)&gi_tab, (void*)&gh_buf, (void*)&h_f32,
    (void*)&h_seq, (void*)&candbufT, (void*)&b_ih, (void*)&b_hh, (void*)&b_out,
    (void*)&out, (void*)&bar
  };
  (void)hipLaunchCooperativeKernel((void*)decode_k, dim3(NBLK), dim3(512), kargs, 0, stream);
}

// Round 11
// 3426.364 us; speedup vs baseline: 1.0211x; 1.0211x over previous
//
#include <hip/hip_runtime.h>
#include <stdint.h>

// MoleculeDecoder r11: r10 with gh_buf reverted to the r8 COALESCED layout.
// r10 post-mortem: WRITE stayed 677MB — the write amplifier was the [b][e][4]
// gh_buf layout (16B-stride 4B stores => 4x partial-line writeback), NOT the
// h-store width. r11: gh writes are 64B-contiguous again (r8 layout); combine
// issues its 3-line gh reads EARLY (overlapped with the candbuf gather).
// Keeps: blocked hi/lo h ring (unpack-free reads), rootless 16-group barrier,
// pair-combine with 2x4B dword h stores, early out-stores.

typedef unsigned long long u64;
typedef unsigned int u32;
typedef unsigned short ush;
typedef _Float16 f16;
using half8 = __attribute__((ext_vector_type(8))) _Float16;
using f32x4 = __attribute__((ext_vector_type(4))) float;

#define E_ 768
#define V_ 8192
#define T_ 256
#define HP 24576            // 32*768 (one h plane, elements)
#define IH_PLANE (2304*768)
#define OUT_PLANE (8192*768)
#define NBLK 256
#define HS_STEP 49152       // ushorts per ring slot (32*768*2)
#define HS_ROW  1536        // ushorts per batch row (768*2)

#define AGENT_LD(p)    __hip_atomic_load((p), __ATOMIC_RELAXED, __HIP_MEMORY_SCOPE_AGENT)
#define AGENT_ST(p,v)  __hip_atomic_store((p), (v), __ATOMIC_RELAXED, __HIP_MEMORY_SCOPE_AGENT)
#define AGENT_ADD(p,v) __hip_atomic_fetch_add((p), (v), __ATOMIC_RELAXED, __HIP_MEMORY_SCOPE_AGENT)

__device__ __forceinline__ f32x4 mfma16(half8 a, half8 b, f32x4 c){
  return __builtin_amdgcn_mfma_f32_16x16x32_f16(a, b, c, 0, 0, 0);
}
__device__ __forceinline__ void split2(float f, f16& hi, f16& lo){
  f16 h = (f16)f; hi = h; lo = (f16)((f - (float)h) * 4096.0f);
}
__device__ __forceinline__ u32 packh(float f){
  f16 h, l; split2(f, h, l);
  return (u32)__builtin_bit_cast(ush, h) | ((u32)__builtin_bit_cast(ush, l) << 16);
}
__device__ __forceinline__ float unpackh(u32 u){
  f16 h = __builtin_bit_cast(f16, (ush)(u & 0xffffu));
  f16 l = __builtin_bit_cast(f16, (ush)(u >> 16));
  return (float)h + (float)l * (1.0f/4096.0f);
}
__device__ __forceinline__ u64 packkey(float f, int v){
  u32 fb = __float_as_uint(f);
  u32 s  = fb ^ ((u32)((int32_t)fb>>31) | 0x80000000u);
  return ((u64)s<<32) | (u64)(0xFFFFFFFFu - (u32)v);   // ties -> smaller idx wins
}

// ---------------- prep: split weights; h0 (f32 + ring slot 0, blocked layout); zero barrier ----------------
#define NB_CONV 1200
#define NB_H0   96
#define NG_IH   221184      // 2304*768/8
#define NG_ALL  1228800     // (2*2304 + 8192)*768/8

__global__ __launch_bounds__(256) void prep_k(
    const float* __restrict__ W_ih, const float* __restrict__ W_hh, const float* __restrict__ W_out,
    const float* __restrict__ latent, const float* __restrict__ W_lat, const float* __restrict__ b_lat,
    f16* __restrict__ Wih_s, f16* __restrict__ Whh_s, f16* __restrict__ Wout_s,
    float* __restrict__ h_f32, u32* __restrict__ h_seq, unsigned* __restrict__ bar)
{
  int blk = blockIdx.x;
  if (blk < NB_CONV){
    for (int g = blk*256 + threadIdx.x; g < NG_ALL; g += NB_CONV*256){
      const float* src; f16* hi; f16* lo; int off;
      if (g < NG_IH)        { src=W_ih; hi=Wih_s; lo=Wih_s+IH_PLANE; off=g*8; }
      else if (g < 2*NG_IH) { src=W_hh; hi=Whh_s; lo=Whh_s+IH_PLANE; off=(g-NG_IH)*8; }
      else                  { src=W_out; hi=Wout_s; lo=Wout_s+OUT_PLANE; off=(g-2*NG_IH)*8; }
      float4 a = *(const float4*)(src+off);
      float4 b = *(const float4*)(src+off+4);
      float fs[8] = {a.x,a.y,a.z,a.w,b.x,b.y,b.z,b.w};
      half8 vh, vl;
      #pragma unroll
      for (int j=0;j<8;j++){ f16 h,l; split2(fs[j],h,l); vh[j]=h; vl[j]=l; }
      *(half8*)(hi+off) = vh;
      *(half8*)(lo+off) = vl;
    }
  } else {
    if (blk==NB_CONV) bar[threadIdx.x] = 0;        // zero all barrier counters
    int tid = (blk-NB_CONV)*256 + threadIdx.x;     // 0..24575
    int b = tid/768, e = tid - b*768;
    const float4* wr = (const float4*)(W_lat + (size_t)e*768);
    const float4* xr = (const float4*)(latent + (size_t)b*768);
    float s0=0.f,s1=0.f,s2=0.f,s3=0.f;
    for (int k=0;k<192;k++){
      float4 w = wr[k]; float4 x = xr[k];
      s0 += w.x*x.x; s1 += w.y*x.y; s2 += w.z*x.z; s3 += w.w*x.w;
    }
    float acc = b_lat[e] + ((s0+s1)+(s2+s3));
    h_f32[b*768+e] = acc;
    f16 hh, ll; split2(acc, hh, ll);
    ush* hw = (ush*)h_seq + b*HS_ROW + (e>>3)*16 + (e&7);   // slot 0, blocked layout
    hw[0] = __builtin_bit_cast(ush, hh);
    hw[8] = __builtin_bit_cast(ush, ll);
  }
}

// ---------------- gi table: gi_tab[tok][2304] = packed(W_ih @ emb[tok]) ----------------
__global__ __launch_bounds__(512) void gitab_k(
    const float* __restrict__ emb, const f16* __restrict__ Wih_s, u32* __restrict__ gi_tab)
{
  __shared__ float red[3][8][2][64][4];
  const int bid = blockIdx.x, tid = threadIdx.x;
  const int tb = bid>>1, half = bid&1;
  const int w = tid>>6, lane = tid&63, col = lane&15, kg = lane>>4, kc = w;
  half8 ah[2][3], al[2][3];
  #pragma unroll
  for (int m=0;m<2;m++)
    #pragma unroll
    for (int i=0;i<3;i++){
      const float* src = emb + (size_t)(tb*32 + m*16 + col)*768 + kc*96 + i*32 + kg*8;
      float4 x0 = *(const float4*)src, x1 = *(const float4*)(src+4);
      float fs[8] = {x0.x,x0.y,x0.z,x0.w,x1.x,x1.y,x1.z,x1.w};
      half8 vh, vl;
      #pragma unroll
      for (int j=0;j<8;j++){ f16 h,l; split2(fs[j],h,l); vh[j]=h; vl[j]=l; }
      ah[m][i]=vh; al[m][i]=vl;
    }
  for (int g=0; g<24; ++g){
    #pragma unroll
    for (int j=0;j<3;j++){
      const int nt = half*72 + g*3 + j;
      f32x4 a0[2], a1[2];
      #pragma unroll
      for (int m=0;m<2;m++){ a0[m]=f32x4{0,0,0,0}; a1[m]=f32x4{0,0,0,0}; }
      #pragma unroll
      for (int i=0;i<3;i++){
        size_t o = (size_t)(nt*16+col)*768 + kc*96 + i*32 + kg*8;
        half8 bh = *(const half8*)(Wih_s + o);
        half8 bl = *(const half8*)(Wih_s + IH_PLANE + o);
        #pragma unroll
        for (int m=0;m<2;m++){
          a0[m] = mfma16(ah[m][i], bh, a0[m]);
          a1[m] = mfma16(ah[m][i], bl, a1[m]);
          a1[m] = mfma16(al[m][i], bh, a1[m]);
        }
      }
      #pragma unroll
      for (int m=0;m<2;m++){
        f32x4 v;
        #pragma unroll
        for (int r=0;r<4;r++) v[r] = a0[m][r] + a1[m][r]*(1.0f/4096.0f);
        *(f32x4*)&red[j][w][m][lane][0] = v;
      }
    }
    __syncthreads();
    if (w < 6){
      const int j = w>>1, m = w&1;
      f32x4 s = {0,0,0,0};
      #pragma unroll
      for (int ww=0; ww<8; ww++) s += *(const f32x4*)&red[j][ww][m][lane][0];
      const int nt = half*72 + g*3 + j;
      const int tokr = tb*32 + m*16 + kg*4;
      #pragma unroll
      for (int r=0;r<4;r++)
        gi_tab[(size_t)(tokr+r)*2304 + nt*16 + col] = packh(s[r]);
    }
    __syncthreads();
  }
}

// ---------------- grid barrier v4: 16 groups x 16 blocks, NO root hop ----------------
__device__ __forceinline__ void gridbar(unsigned* bar, unsigned target){
  __syncthreads();   // drains each wave's vmem ops (sc1 stores now globally visible)
  if (threadIdx.x < 64){
    if (threadIdx.x == 0) AGENT_ADD(&bar[(blockIdx.x & 15)*16], 1u);
    const u32 goal = 16u*target;
    const int lane = threadIdx.x;
    for(;;){
      u32 v = (lane < 16) ? AGENT_LD(&bar[lane*16]) : goal;
      if (__all(v >= goal)) break;
      __builtin_amdgcn_s_sleep(1);
    }
  }
  __syncthreads();
}

// ---------------- persistent decode kernel (cooperative, 256 x 512) ----------------
__global__ __launch_bounds__(512, 2) void decode_k(
    const f16* __restrict__ Wout_s, const f16* __restrict__ Whh_s, const u32* __restrict__ gi_tab,
    float* __restrict__ gh_buf, const float* __restrict__ h_f32, u32* __restrict__ h_seq,
    u64* __restrict__ candbufT, const float* __restrict__ b_ih, const float* __restrict__ b_hh,
    const float* __restrict__ b_out, float* __restrict__ out, unsigned* __restrict__ bar)
{
  __shared__ float red[3][8][2][64][4];   // 48 KB
  __shared__ u64 amkey[32];
  const int bid = blockIdx.x, tid = threadIdx.x;
  const int w = tid>>6, lane = tid&63, col = lane&15, kg = lane>>4, kc = w;

  // One-time L2/L1 invalidate: kill any stale (poison) lines before cached h reads.
  __builtin_amdgcn_fence(__ATOMIC_ACQUIRE, "agent");
  __syncthreads();

  // ---- persistent B fragments (held in VGPRs for the whole kernel) ----
  const f16* srcH[3] = {Wout_s, Wout_s, (bid<144)? Whh_s : Wout_s};
  const f16* srcL[3] = {Wout_s+OUT_PLANE, Wout_s+OUT_PLANE,
                        (bid<144)? Whh_s+IH_PLANE : Wout_s+OUT_PLANE};
  const int  rowb[3] = {bid*16, 4096+bid*16, (bid<144)? bid*16 : 0};
  half8 bf_h[3][3], bf_l[3][3];
  #pragma unroll
  for (int s=0;s<3;s++)
    #pragma unroll
    for (int i=0;i<3;i++){
      size_t o = (size_t)(rowb[s]+col)*768 + kc*96 + i*32 + kg*8;
      bf_h[s][i] = *(const half8*)(srcH[s] + o);
      bf_l[s][i] = *(const half8*)(srcL[s] + o);
    }
  float bo_reg[2];
  bo_reg[0] = b_out[bid*16 + col];
  bo_reg[1] = b_out[4096 + bid*16 + col];

  // combine-role hoists: blocks 0..47, threads 0..255 own element PAIR (cb, ce..ce+1)
  const bool is_cmb = (bid < 48) && (tid < 256);
  int cb = 0, ce = 0; float hr0 = 0.f, hr1 = 0.f;
  float bi0r=0,bi0z=0,bi0n=0, bi1r=0,bi1z=0,bi1n=0;
  float bh0r=0,bh0z=0,bh0n=0, bh1r=0,bh1z=0,bh1n=0;
  if (is_cmb){
    int p = bid*256 + tid;          // pair index, elements 2p, 2p+1
    int e0 = 2*p;
    cb = e0/768; ce = e0 - cb*768;  // ce even; 768%128==0 => cb wave-uniform
    hr0 = h_f32[cb*768 + ce];  hr1 = h_f32[cb*768 + ce + 1];
    bi0r=b_ih[ce];      bi0z=b_ih[768+ce];      bi0n=b_ih[1536+ce];
    bi1r=b_ih[ce+1];    bi1z=b_ih[768+ce+1];    bi1n=b_ih[1536+ce+1];
    bh0r=b_hh[ce];      bh0z=b_hh[768+ce];      bh0n=b_hh[1536+ce];
    bh1r=b_hh[ce+1];    bh1z=b_hh[768+ce+1];    bh1n=b_hh[1536+ce+1];
  }
  // gh writer column (blocks 0..143, slot-2 reducer wave): r8 coalesced layout
  const int gr2 = bid*16 + col;

  unsigned bt = 0;
  for (int t=0; t<=256; ++t){
    // =================== phase A ===================
    if (tid < 32) amkey[tid] = 0;
    // A-frags: DIRECT half8 cached loads from this step's ring slot
    const ush* h16 = (const ush*)h_seq + (size_t)t*HS_STEP;
    half8 ah[2][3], al[2][3];
    #pragma unroll
    for (int m=0;m<2;m++)
      #pragma unroll
      for (int i=0;i<3;i++){
        const ush* hp = h16 + (m*16+col)*HS_ROW + (kc*12+i*4+kg)*16;
        ah[m][i] = *(const half8*)(hp);
        al[m][i] = *(const half8*)(hp+8);
      }
    #pragma unroll
    for (int s=0;s<3;s++){
      f32x4 a0[2], a1[2];
      #pragma unroll
      for (int m=0;m<2;m++){ a0[m]=f32x4{0,0,0,0}; a1[m]=f32x4{0,0,0,0}; }
      #pragma unroll
      for (int i=0;i<3;i++)
        #pragma unroll
        for (int m=0;m<2;m++){
          a0[m] = mfma16(ah[m][i], bf_h[s][i], a0[m]);
          a1[m] = mfma16(ah[m][i], bf_l[s][i], a1[m]);
          a1[m] = mfma16(al[m][i], bf_h[s][i], a1[m]);
        }
      #pragma unroll
      for (int m=0;m<2;m++){
        f32x4 v;
        #pragma unroll
        for (int r=0;r<4;r++) v[r] = a0[m][r] + a1[m][r]*(1.0f/4096.0f);
        *(f32x4*)&red[s][w][m][lane][0] = v;
      }
    }
    __syncthreads();
    float sv[2][4];                       // deferred logit stores (cross-barrier)
    bool have_out = false;
    if (w < 3){
      const int s = w;
      float vm[2][4];
      #pragma unroll
      for (int m=0;m<2;m++){
        f32x4 sum = {0,0,0,0};
        #pragma unroll
        for (int ww=0; ww<8; ww++) sum += *(const f32x4*)&red[s][ww][m][lane][0];
        #pragma unroll
        for (int r=0;r<4;r++) vm[m][r] = sum[r];
      }
      if (s < 2){
        if (t >= 1){
          have_out = true;
          const int v = s*4096 + bid*16 + col;
          const float bo = bo_reg[s];
          #pragma unroll
          for (int m=0;m<2;m++)
            #pragma unroll
            for (int r=0;r<4;r++){
              const int b = m*16 + kg*4 + r;
              const float p = vm[m][r] + bo;
              sv[m][r] = p;
              u64 key = packkey(p, v);
              #pragma unroll
              for (int off=1; off<16; off<<=1){
                u64 o = __shfl_xor((unsigned long long)key, off);
                if (o > key) key = o;
              }
              if (col == 0) atomicMax(&amkey[b], key);
            }
        }
      } else if (bid < 144){
        // gh -> r8 layout [b][2304]: 16 consecutive floats per lane-group = 64B line
        #pragma unroll
        for (int m=0;m<2;m++)
          #pragma unroll
          for (int r=0;r<4;r++)
            AGENT_ST(&gh_buf[(size_t)(m*16+kg*4+r)*2304 + gr2], vm[m][r]);
      }
    }
    __syncthreads();                      // amkey final
    if (t >= 1 && tid < 32) AGENT_ST(&candbufT[(size_t)tid*256 + bid], amkey[tid]);
    if (t == 256){                        // last step: store logits, done
      if (have_out){
        const int v = w*4096 + bid*16 + col;
        #pragma unroll
        for (int m=0;m<2;m++)
          #pragma unroll
          for (int r=0;r<4;r++)
            out[(size_t)(m*16+kg*4+r)*((size_t)T_*V_) + (size_t)(t-1)*V_ + v] = sv[m][r];
      }
      break;
    }
    gridbar(bar, ++bt);
    // =================== out stores + phase B ===================
    if (bid >= 48){
      if (have_out){
        const int v = w*4096 + bid*16 + col;
        #pragma unroll
        for (int m=0;m<2;m++)
          #pragma unroll
          for (int r=0;r<4;r++)
            out[(size_t)(m*16+kg*4+r)*((size_t)T_*V_) + (size_t)(t-1)*V_ + v] = sv[m][r];
      }
    } else {
      // early issue (independent of tok): gh reads (3 lines, pair-adjacent) overlap gather
      float g0r=0,g0z=0,g0n=0, g1r=0,g1z=0,g1n=0;
      if (is_cmb){
        const float* hb = gh_buf + (size_t)cb*2304 + ce;
        g0r = AGENT_LD(hb);        g1r = AGENT_LD(hb + 1);
        g0z = AGENT_LD(hb + 768);  g1z = AGENT_LD(hb + 769);
        g0n = AGENT_LD(hb + 1536); g1n = AGENT_LD(hb + 1537);
      }
      if (have_out){                      // overlap HBM acks with the gather
        const int v = w*4096 + bid*16 + col;
        #pragma unroll
        for (int m=0;m<2;m++)
          #pragma unroll
          for (int r=0;r<4;r++)
            out[(size_t)(m*16+kg*4+r)*((size_t)T_*V_) + (size_t)(t-1)*V_ + v] = sv[m][r];
      }
      int tok = 1;
      if (t > 0 && tid < 256){
        u64 k = 0;
        #pragma unroll
        for (int j=0;j<4;j++){
          u64 c = AGENT_LD(&candbufT[(size_t)cb*256 + lane + 64*j]);
          if (c > k) k = c;
        }
        #pragma unroll
        for (int off=1; off<64; off<<=1){
          u64 o = __shfl_xor((unsigned long long)k, off);
          if (o > k) k = o;
        }
        tok = (int)(0xFFFFFFFFu - (unsigned)(k & 0xFFFFFFFFull));
      }
      if (is_cmb){
        const u32* gp = gi_tab + (size_t)tok*2304 + ce;   // plain cached (read-only)
        u64 gR = *(const u64*)(gp);
        u64 gZ = *(const u64*)(gp + 768);
        u64 gN = *(const u64*)(gp + 1536);
        const float gi0r = unpackh((u32)gR)      + bi0r;
        const float gi1r = unpackh((u32)(gR>>32))+ bi1r;
        const float gi0z = unpackh((u32)gZ)      + bi0z;
        const float gi1z = unpackh((u32)(gZ>>32))+ bi1z;
        const float gi0n = unpackh((u32)gN)      + bi0n;
        const float gi1n = unpackh((u32)(gN>>32))+ bi1n;
        const float r0 = 1.0f/(1.0f+expf(-(gi0r + g0r + bh0r)));
        const float z0 = 1.0f/(1.0f+expf(-(gi0z + g0z + bh0z)));
        const float n0 = tanhf(gi0n + r0*(g0n + bh0n));
        hr0 = (1.0f-z0)*n0 + z0*hr0;
        const float r1 = 1.0f/(1.0f+expf(-(gi1r + g1r + bh1r)));
        const float z1 = 1.0f/(1.0f+expf(-(gi1z + g1z + bh1z)));
        const float n1 = tanhf(gi1n + r1*(g1n + bh1n));
        hr1 = (1.0f-z1)*n1 + z1*hr1;
        // h store: blocked hi/lo layout, 2x4B dword AGENT_ST (pair-packed)
        f16 h0,l0,h1,l1; split2(hr0,h0,l0); split2(hr1,h1,l1);
        u32 wHi = (u32)__builtin_bit_cast(ush,h0) | ((u32)__builtin_bit_cast(ush,h1)<<16);
        u32 wLo = (u32)__builtin_bit_cast(ush,l0) | ((u32)__builtin_bit_cast(ush,l1)<<16);
        u32* hw = (u32*)((ush*)h_seq + (size_t)(t+1)*HS_STEP + cb*HS_ROW + (ce>>3)*16 + (ce&7));
        AGENT_ST(hw,     wHi);
        AGENT_ST(hw + 4, wLo);            // +8 ushorts = +4 u32
      }
    }
    gridbar(bar, ++bt);
  }
}

// ---------------- host ----------------
extern "C" void kernel_launch(void* const* d_in, const int* in_sizes, int n_in,
                              void* d_out, int out_size, void* d_ws, size_t ws_size,
                              hipStream_t stream){
  const float* latent = (const float*)d_in[0];
  const float* W_lat  = (const float*)d_in[1];
  const float* b_lat  = (const float*)d_in[2];
  const float* emb    = (const float*)d_in[3];
  const float* W_ih   = (const float*)d_in[4];
  const float* W_hh   = (const float*)d_in[5];
  const float* b_ih   = (const float*)d_in[6];
  const float* b_hh   = (const float*)d_in[7];
  const float* W_out  = (const float*)d_in[8];
  const float* b_out  = (const float*)d_in[9];
  float* out = (float*)d_out;
  (void)in_sizes; (void)n_in; (void)out_size; (void)ws_size;

  char* ws = (char*)d_ws;
  size_t off = 0;
  auto carve = [&](size_t bytes)->char*{
    char* p = ws + off; off += (bytes + 255) & ~(size_t)255; return p;
  };
  f16*      Wih_s  = (f16*)     carve((size_t)2*IH_PLANE*2);    //  7.08 MB
  f16*      Whh_s  = (f16*)     carve((size_t)2*IH_PLANE*2);    //  7.08 MB
  f16*      Wout_s = (f16*)     carve((size_t)2*OUT_PLANE*2);   // 25.17 MB
  u32*      gi_tab = (u32*)     carve((size_t)8192*2304*4);     // 37.75 MB (packed)
  float*    gh_buf = (float*)   carve((size_t)32*2304*4);       //  0.29 MB (r8 layout)
  float*    h_f32  = (float*)   carve((size_t)HP*4);            //  0.10 MB
  u32*      h_seq  = (u32*)     carve((size_t)257*HP*4);        // 25.26 MB ring (blocked hi/lo)
  u64*      candbufT=(u64*)     carve((size_t)32*256*8);        //  0.07 MB
  unsigned* bar    = (unsigned*)carve(2048);
  // total ~103 MB of d_ws

  hipLaunchKernelGGL(prep_k, dim3(NB_CONV+NB_H0), dim3(256), 0, stream,
                     W_ih, W_hh, W_out, latent, W_lat, b_lat,
                     Wih_s, Whh_s, Wout_s, h_f32, h_seq, bar);
  hipLaunchKernelGGL(gitab_k, dim3(512), dim3(512), 0, stream, emb, Wih_s, gi_tab);

  void* kargs[] = {
    (void*)&Wout_s, (void*)&Whh_s, (void*)&gi_tab, (void*)&gh_buf, (void*)&h_f32,
    (void*)&h_seq, (void*)&candbufT, (void*)&b_ih, (void*)&b_hh, (void*)&b_out,
    (void*)&out, (void*)&bar
  };
  (void)hipLaunchCooperativeKernel((void*)decode_k, dim3(NBLK), dim3(512), kargs, 0, stream);
}

// Round 12
// 3184.101 us; speedup vs baseline: 1.0988x; 1.0761x over previous
//
#include <hip/hip_runtime.h>
#include <stdint.h>

// MoleculeDecoder r12: r11 with the r8 TWO-LEVEL TREE barrier restored.
// r11 post-mortem: fixing gh write-amp (WRITE 677->455MB) didn't move time =>
// the r9 "rootless" barrier is the r8->r9 regression: its detect wave polls 16
// cache lines per iteration x 256 blocks (16x poll traffic on the L3 atomic
// path). r12 = r11 (blocked hi/lo ring, pair-combine, coalesced gh, early
// issue, packed gi) + r8 barrier (arrive on 8 group lines, poll ONE root line).

typedef unsigned long long u64;
typedef unsigned int u32;
typedef unsigned short ush;
typedef _Float16 f16;
using half8 = __attribute__((ext_vector_type(8))) _Float16;
using f32x4 = __attribute__((ext_vector_type(4))) float;

#define E_ 768
#define V_ 8192
#define T_ 256
#define HP 24576            // 32*768 (one h plane, elements)
#define IH_PLANE (2304*768)
#define OUT_PLANE (8192*768)
#define NBLK 256
#define HS_STEP 49152       // ushorts per ring slot (32*768*2)
#define HS_ROW  1536        // ushorts per batch row (768*2)

#define AGENT_LD(p)    __hip_atomic_load((p), __ATOMIC_RELAXED, __HIP_MEMORY_SCOPE_AGENT)
#define AGENT_ST(p,v)  __hip_atomic_store((p), (v), __ATOMIC_RELAXED, __HIP_MEMORY_SCOPE_AGENT)
#define AGENT_ADD(p,v) __hip_atomic_fetch_add((p), (v), __ATOMIC_RELAXED, __HIP_MEMORY_SCOPE_AGENT)

__device__ __forceinline__ f32x4 mfma16(half8 a, half8 b, f32x4 c){
  return __builtin_amdgcn_mfma_f32_16x16x32_f16(a, b, c, 0, 0, 0);
}
__device__ __forceinline__ void split2(float f, f16& hi, f16& lo){
  f16 h = (f16)f; hi = h; lo = (f16)((f - (float)h) * 4096.0f);
}
__device__ __forceinline__ u32 packh(float f){
  f16 h, l; split2(f, h, l);
  return (u32)__builtin_bit_cast(ush, h) | ((u32)__builtin_bit_cast(ush, l) << 16);
}
__device__ __forceinline__ float unpackh(u32 u){
  f16 h = __builtin_bit_cast(f16, (ush)(u & 0xffffu));
  f16 l = __builtin_bit_cast(f16, (ush)(u >> 16));
  return (float)h + (float)l * (1.0f/4096.0f);
}
__device__ __forceinline__ u64 packkey(float f, int v){
  u32 fb = __float_as_uint(f);
  u32 s  = fb ^ ((u32)((int32_t)fb>>31) | 0x80000000u);
  return ((u64)s<<32) | (u64)(0xFFFFFFFFu - (u32)v);   // ties -> smaller idx wins
}

// ---------------- prep: split weights; h0 (f32 + ring slot 0, blocked layout); zero barrier ----------------
#define NB_CONV 1200
#define NB_H0   96
#define NG_IH   221184      // 2304*768/8
#define NG_ALL  1228800     // (2*2304 + 8192)*768/8

__global__ __launch_bounds__(256) void prep_k(
    const float* __restrict__ W_ih, const float* __restrict__ W_hh, const float* __restrict__ W_out,
    const float* __restrict__ latent, const float* __restrict__ W_lat, const float* __restrict__ b_lat,
    f16* __restrict__ Wih_s, f16* __restrict__ Whh_s, f16* __restrict__ Wout_s,
    float* __restrict__ h_f32, u32* __restrict__ h_seq, unsigned* __restrict__ bar)
{
  int blk = blockIdx.x;
  if (blk < NB_CONV){
    for (int g = blk*256 + threadIdx.x; g < NG_ALL; g += NB_CONV*256){
      const float* src; f16* hi; f16* lo; int off;
      if (g < NG_IH)        { src=W_ih; hi=Wih_s; lo=Wih_s+IH_PLANE; off=g*8; }
      else if (g < 2*NG_IH) { src=W_hh; hi=Whh_s; lo=Whh_s+IH_PLANE; off=(g-NG_IH)*8; }
      else                  { src=W_out; hi=Wout_s; lo=Wout_s+OUT_PLANE; off=(g-2*NG_IH)*8; }
      float4 a = *(const float4*)(src+off);
      float4 b = *(const float4*)(src+off+4);
      float fs[8] = {a.x,a.y,a.z,a.w,b.x,b.y,b.z,b.w};
      half8 vh, vl;
      #pragma unroll
      for (int j=0;j<8;j++){ f16 h,l; split2(fs[j],h,l); vh[j]=h; vl[j]=l; }
      *(half8*)(hi+off) = vh;
      *(half8*)(lo+off) = vl;
    }
  } else {
    if (blk==NB_CONV) bar[threadIdx.x] = 0;        // zero all barrier counters
    int tid = (blk-NB_CONV)*256 + threadIdx.x;     // 0..24575
    int b = tid/768, e = tid - b*768;
    const float4* wr = (const float4*)(W_lat + (size_t)e*768);
    const float4* xr = (const float4*)(latent + (size_t)b*768);
    float s0=0.f,s1=0.f,s2=0.f,s3=0.f;
    for (int k=0;k<192;k++){
      float4 w = wr[k]; float4 x = xr[k];
      s0 += w.x*x.x; s1 += w.y*x.y; s2 += w.z*x.z; s3 += w.w*x.w;
    }
    float acc = b_lat[e] + ((s0+s1)+(s2+s3));
    h_f32[b*768+e] = acc;
    f16 hh, ll; split2(acc, hh, ll);
    ush* hw = (ush*)h_seq + b*HS_ROW + (e>>3)*16 + (e&7);   // slot 0, blocked layout
    hw[0] = __builtin_bit_cast(ush, hh);
    hw[8] = __builtin_bit_cast(ush, ll);
  }
}

// ---------------- gi table: gi_tab[tok][2304] = packed(W_ih @ emb[tok]) ----------------
__global__ __launch_bounds__(512) void gitab_k(
    const float* __restrict__ emb, const f16* __restrict__ Wih_s, u32* __restrict__ gi_tab)
{
  __shared__ float red[3][8][2][64][4];
  const int bid = blockIdx.x, tid = threadIdx.x;
  const int tb = bid>>1, half = bid&1;
  const int w = tid>>6, lane = tid&63, col = lane&15, kg = lane>>4, kc = w;
  half8 ah[2][3], al[2][3];
  #pragma unroll
  for (int m=0;m<2;m++)
    #pragma unroll
    for (int i=0;i<3;i++){
      const float* src = emb + (size_t)(tb*32 + m*16 + col)*768 + kc*96 + i*32 + kg*8;
      float4 x0 = *(const float4*)src, x1 = *(const float4*)(src+4);
      float fs[8] = {x0.x,x0.y,x0.z,x0.w,x1.x,x1.y,x1.z,x1.w};
      half8 vh, vl;
      #pragma unroll
      for (int j=0;j<8;j++){ f16 h,l; split2(fs[j],h,l); vh[j]=h; vl[j]=l; }
      ah[m][i]=vh; al[m][i]=vl;
    }
  for (int g=0; g<24; ++g){
    #pragma unroll
    for (int j=0;j<3;j++){
      const int nt = half*72 + g*3 + j;
      f32x4 a0[2], a1[2];
      #pragma unroll
      for (int m=0;m<2;m++){ a0[m]=f32x4{0,0,0,0}; a1[m]=f32x4{0,0,0,0}; }
      #pragma unroll
      for (int i=0;i<3;i++){
        size_t o = (size_t)(nt*16+col)*768 + kc*96 + i*32 + kg*8;
        half8 bh = *(const half8*)(Wih_s + o);
        half8 bl = *(const half8*)(Wih_s + IH_PLANE + o);
        #pragma unroll
        for (int m=0;m<2;m++){
          a0[m] = mfma16(ah[m][i], bh, a0[m]);
          a1[m] = mfma16(ah[m][i], bl, a1[m]);
          a1[m] = mfma16(al[m][i], bh, a1[m]);
        }
      }
      #pragma unroll
      for (int m=0;m<2;m++){
        f32x4 v;
        #pragma unroll
        for (int r=0;r<4;r++) v[r] = a0[m][r] + a1[m][r]*(1.0f/4096.0f);
        *(f32x4*)&red[j][w][m][lane][0] = v;
      }
    }
    __syncthreads();
    if (w < 6){
      const int j = w>>1, m = w&1;
      f32x4 s = {0,0,0,0};
      #pragma unroll
      for (int ww=0; ww<8; ww++) s += *(const f32x4*)&red[j][ww][m][lane][0];
      const int nt = half*72 + g*3 + j;
      const int tokr = tb*32 + m*16 + kg*4;
      #pragma unroll
      for (int r=0;r<4;r++)
        gi_tab[(size_t)(tokr+r)*2304 + nt*16 + col] = packh(s[r]);
    }
    __syncthreads();
  }
}

// ---------------- grid barrier (r8 tree): 8 groups x 32, poll ONE root line ----------------
__device__ __forceinline__ void gridbar(unsigned* bar, unsigned target){
  __syncthreads();   // drains each wave's vmem ops (sc1 stores now globally visible)
  if (threadIdx.x == 0){
    const int g = blockIdx.x & 7;
    unsigned old = AGENT_ADD(&bar[g*16], 1u);
    if (old == 32u*target - 1u)            // last arriver of this group this round
      AGENT_ADD(&bar[128], 1u);
    int spins = 0;
    while (AGENT_LD(&bar[128]) < 8u*target){
      __builtin_amdgcn_s_sleep(1);
      if ((++spins & 2047) == 0)           // liveness insurance (RMW always coherent)
        AGENT_ADD(&bar[128], 0u);
    }
  }
  __syncthreads();
}

// ---------------- persistent decode kernel (cooperative, 256 x 512) ----------------
__global__ __launch_bounds__(512, 2) void decode_k(
    const f16* __restrict__ Wout_s, const f16* __restrict__ Whh_s, const u32* __restrict__ gi_tab,
    float* __restrict__ gh_buf, const float* __restrict__ h_f32, u32* __restrict__ h_seq,
    u64* __restrict__ candbufT, const float* __restrict__ b_ih, const float* __restrict__ b_hh,
    const float* __restrict__ b_out, float* __restrict__ out, unsigned* __restrict__ bar)
{
  __shared__ float red[3][8][2][64][4];   // 48 KB
  __shared__ u64 amkey[32];
  const int bid = blockIdx.x, tid = threadIdx.x;
  const int w = tid>>6, lane = tid&63, col = lane&15, kg = lane>>4, kc = w;

  // One-time L2/L1 invalidate: kill any stale (poison) lines before cached h reads.
  __builtin_amdgcn_fence(__ATOMIC_ACQUIRE, "agent");
  __syncthreads();

  // ---- persistent B fragments (held in VGPRs for the whole kernel) ----
  const f16* srcH[3] = {Wout_s, Wout_s, (bid<144)? Whh_s : Wout_s};
  const f16* srcL[3] = {Wout_s+OUT_PLANE, Wout_s+OUT_PLANE,
                        (bid<144)? Whh_s+IH_PLANE : Wout_s+OUT_PLANE};
  const int  rowb[3] = {bid*16, 4096+bid*16, (bid<144)? bid*16 : 0};
  half8 bf_h[3][3], bf_l[3][3];
  #pragma unroll
  for (int s=0;s<3;s++)
    #pragma unroll
    for (int i=0;i<3;i++){
      size_t o = (size_t)(rowb[s]+col)*768 + kc*96 + i*32 + kg*8;
      bf_h[s][i] = *(const half8*)(srcH[s] + o);
      bf_l[s][i] = *(const half8*)(srcL[s] + o);
    }
  float bo_reg[2];
  bo_reg[0] = b_out[bid*16 + col];
  bo_reg[1] = b_out[4096 + bid*16 + col];

  // combine-role hoists: blocks 0..47, threads 0..255 own element PAIR (cb, ce..ce+1)
  const bool is_cmb = (bid < 48) && (tid < 256);
  int cb = 0, ce = 0; float hr0 = 0.f, hr1 = 0.f;
  float bi0r=0,bi0z=0,bi0n=0, bi1r=0,bi1z=0,bi1n=0;
  float bh0r=0,bh0z=0,bh0n=0, bh1r=0,bh1z=0,bh1n=0;
  if (is_cmb){
    int p = bid*256 + tid;          // pair index, elements 2p, 2p+1
    int e0 = 2*p;
    cb = e0/768; ce = e0 - cb*768;  // ce even; 768%128==0 => cb wave-uniform
    hr0 = h_f32[cb*768 + ce];  hr1 = h_f32[cb*768 + ce + 1];
    bi0r=b_ih[ce];      bi0z=b_ih[768+ce];      bi0n=b_ih[1536+ce];
    bi1r=b_ih[ce+1];    bi1z=b_ih[768+ce+1];    bi1n=b_ih[1536+ce+1];
    bh0r=b_hh[ce];      bh0z=b_hh[768+ce];      bh0n=b_hh[1536+ce];
    bh1r=b_hh[ce+1];    bh1z=b_hh[768+ce+1];    bh1n=b_hh[1536+ce+1];
  }
  // gh writer column (blocks 0..143, slot-2 reducer wave): coalesced layout
  const int gr2 = bid*16 + col;

  unsigned bt = 0;
  for (int t=0; t<=256; ++t){
    // =================== phase A ===================
    if (tid < 32) amkey[tid] = 0;
    // A-frags: DIRECT half8 cached loads from this step's ring slot
    const ush* h16 = (const ush*)h_seq + (size_t)t*HS_STEP;
    half8 ah[2][3], al[2][3];
    #pragma unroll
    for (int m=0;m<2;m++)
      #pragma unroll
      for (int i=0;i<3;i++){
        const ush* hp = h16 + (m*16+col)*HS_ROW + (kc*12+i*4+kg)*16;
        ah[m][i] = *(const half8*)(hp);
        al[m][i] = *(const half8*)(hp+8);
      }
    #pragma unroll
    for (int s=0;s<3;s++){
      f32x4 a0[2], a1[2];
      #pragma unroll
      for (int m=0;m<2;m++){ a0[m]=f32x4{0,0,0,0}; a1[m]=f32x4{0,0,0,0}; }
      #pragma unroll
      for (int i=0;i<3;i++)
        #pragma unroll
        for (int m=0;m<2;m++){
          a0[m] = mfma16(ah[m][i], bf_h[s][i], a0[m]);
          a1[m] = mfma16(ah[m][i], bf_l[s][i], a1[m]);
          a1[m] = mfma16(al[m][i], bf_h[s][i], a1[m]);
        }
      #pragma unroll
      for (int m=0;m<2;m++){
        f32x4 v;
        #pragma unroll
        for (int r=0;r<4;r++) v[r] = a0[m][r] + a1[m][r]*(1.0f/4096.0f);
        *(f32x4*)&red[s][w][m][lane][0] = v;
      }
    }
    __syncthreads();
    float sv[2][4];                       // deferred logit stores (cross-barrier)
    bool have_out = false;
    if (w < 3){
      const int s = w;
      float vm[2][4];
      #pragma unroll
      for (int m=0;m<2;m++){
        f32x4 sum = {0,0,0,0};
        #pragma unroll
        for (int ww=0; ww<8; ww++) sum += *(const f32x4*)&red[s][ww][m][lane][0];
        #pragma unroll
        for (int r=0;r<4;r++) vm[m][r] = sum[r];
      }
      if (s < 2){
        if (t >= 1){
          have_out = true;
          const int v = s*4096 + bid*16 + col;
          const float bo = bo_reg[s];
          #pragma unroll
          for (int m=0;m<2;m++)
            #pragma unroll
            for (int r=0;r<4;r++){
              const int b = m*16 + kg*4 + r;
              const float p = vm[m][r] + bo;
              sv[m][r] = p;
              u64 key = packkey(p, v);
              #pragma unroll
              for (int off=1; off<16; off<<=1){
                u64 o = __shfl_xor((unsigned long long)key, off);
                if (o > key) key = o;
              }
              if (col == 0) atomicMax(&amkey[b], key);
            }
        }
      } else if (bid < 144){
        // gh coalesced layout [b][2304]: 16 consecutive floats per lane-group
        #pragma unroll
        for (int m=0;m<2;m++)
          #pragma unroll
          for (int r=0;r<4;r++)
            AGENT_ST(&gh_buf[(size_t)(m*16+kg*4+r)*2304 + gr2], vm[m][r]);
      }
    }
    __syncthreads();                      // amkey final
    if (t >= 1 && tid < 32) AGENT_ST(&candbufT[(size_t)tid*256 + bid], amkey[tid]);
    if (t == 256){                        // last step: store logits, done
      if (have_out){
        const int v = w*4096 + bid*16 + col;
        #pragma unroll
        for (int m=0;m<2;m++)
          #pragma unroll
          for (int r=0;r<4;r++)
            out[(size_t)(m*16+kg*4+r)*((size_t)T_*V_) + (size_t)(t-1)*V_ + v] = sv[m][r];
      }
      break;
    }
    gridbar(bar, ++bt);
    // =================== out stores + phase B ===================
    if (bid >= 48){
      if (have_out){
        const int v = w*4096 + bid*16 + col;
        #pragma unroll
        for (int m=0;m<2;m++)
          #pragma unroll
          for (int r=0;r<4;r++)
            out[(size_t)(m*16+kg*4+r)*((size_t)T_*V_) + (size_t)(t-1)*V_ + v] = sv[m][r];
      }
    } else {
      // early issue (independent of tok): gh reads (3 lines, pair-adjacent) overlap gather
      float g0r=0,g0z=0,g0n=0, g1r=0,g1z=0,g1n=0;
      if (is_cmb){
        const float* hb = gh_buf + (size_t)cb*2304 + ce;
        g0r = AGENT_LD(hb);        g1r = AGENT_LD(hb + 1);
        g0z = AGENT_LD(hb + 768);  g1z = AGENT_LD(hb + 769);
        g0n = AGENT_LD(hb + 1536); g1n = AGENT_LD(hb + 1537);
      }
      if (have_out){                      // overlap HBM acks with the gather
        const int v = w*4096 + bid*16 + col;
        #pragma unroll
        for (int m=0;m<2;m++)
          #pragma unroll
          for (int r=0;r<4;r++)
            out[(size_t)(m*16+kg*4+r)*((size_t)T_*V_) + (size_t)(t-1)*V_ + v] = sv[m][r];
      }
      int tok = 1;
      if (t > 0 && tid < 256){
        u64 k = 0;
        #pragma unroll
        for (int j=0;j<4;j++){
          u64 c = AGENT_LD(&candbufT[(size_t)cb*256 + lane + 64*j]);
          if (c > k) k = c;
        }
        #pragma unroll
        for (int off=1; off<64; off<<=1){
          u64 o = __shfl_xor((unsigned long long)k, off);
          if (o > k) k = o;
        }
        tok = (int)(0xFFFFFFFFu - (unsigned)(k & 0xFFFFFFFFull));
      }
      if (is_cmb){
        const u32* gp = gi_tab + (size_t)tok*2304 + ce;   // plain cached (read-only)
        u64 gR = *(const u64*)(gp);
        u64 gZ = *(const u64*)(gp + 768);
        u64 gN = *(const u64*)(gp + 1536);
        const float gi0r = unpackh((u32)gR)      + bi0r;
        const float gi1r = unpackh((u32)(gR>>32))+ bi1r;
        const float gi0z = unpackh((u32)gZ)      + bi0z;
        const float gi1z = unpackh((u32)(gZ>>32))+ bi1z;
        const float gi0n = unpackh((u32)gN)      + bi0n;
        const float gi1n = unpackh((u32)(gN>>32))+ bi1n;
        const float r0 = 1.0f/(1.0f+expf(-(gi0r + g0r + bh0r)));
        const float z0 = 1.0f/(1.0f+expf(-(gi0z + g0z + bh0z)));
        const float n0 = tanhf(gi0n + r0*(g0n + bh0n));
        hr0 = (1.0f-z0)*n0 + z0*hr0;
        const float r1 = 1.0f/(1.0f+expf(-(gi1r + g1r + bh1r)));
        const float z1 = 1.0f/(1.0f+expf(-(gi1z + g1z + bh1z)));
        const float n1 = tanhf(gi1n + r1*(g1n + bh1n));
        hr1 = (1.0f-z1)*n1 + z1*hr1;
        // h store: blocked hi/lo layout, 2x4B dword AGENT_ST (pair-packed)
        f16 h0,l0,h1,l1; split2(hr0,h0,l0); split2(hr1,h1,l1);
        u32 wHi = (u32)__builtin_bit_cast(ush,h0) | ((u32)__builtin_bit_cast(ush,h1)<<16);
        u32 wLo = (u32)__builtin_bit_cast(ush,l0) | ((u32)__builtin_bit_cast(ush,l1)<<16);
        u32* hw = (u32*)((ush*)h_seq + (size_t)(t+1)*HS_STEP + cb*HS_ROW + (ce>>3)*16 + (ce&7));
        AGENT_ST(hw,     wHi);
        AGENT_ST(hw + 4, wLo);            // +8 ushorts = +4 u32
      }
    }
    gridbar(bar, ++bt);
  }
}

// ---------------- host ----------------
extern "C" void kernel_launch(void* const* d_in, const int* in_sizes, int n_in,
                              void* d_out, int out_size, void* d_ws, size_t ws_size,
                              hipStream_t stream){
  const float* latent = (const float*)d_in[0];
  const float* W_lat  = (const float*)d_in[1];
  const float* b_lat  = (const float*)d_in[2];
  const float* emb    = (const float*)d_in[3];
  const float* W_ih   = (const float*)d_in[4];
  const float* W_hh   = (const float*)d_in[5];
  const float* b_ih   = (const float*)d_in[6];
  const float* b_hh   = (const float*)d_in[7];
  const float* W_out  = (const float*)d_in[8];
  const float* b_out  = (const float*)d_in[9];
  float* out = (float*)d_out;
  (void)in_sizes; (void)n_in; (void)out_size; (void)ws_size;

  char* ws = (char*)d_ws;
  size_t off = 0;
  auto carve = [&](size_t bytes)->char*{
    char* p = ws + off; off += (bytes + 255) & ~(size_t)255; return p;
  };
  f16*      Wih_s  = (f16*)     carve((size_t)2*IH_PLANE*2);    //  7.08 MB
  f16*      Whh_s  = (f16*)     carve((size_t)2*IH_PLANE*2);    //  7.08 MB
  f16*      Wout_s = (f16*)     carve((size_t)2*OUT_PLANE*2);   // 25.17 MB
  u32*      gi_tab = (u32*)     carve((size_t)8192*2304*4);     // 37.75 MB (packed)
  float*    gh_buf = (float*)   carve((size_t)32*2304*4);       //  0.29 MB (coalesced)
  float*    h_f32  = (float*)   carve((size_t)HP*4);            //  0.10 MB
  u32*      h_seq  = (u32*)     carve((size_t)257*HP*4);        // 25.26 MB ring (blocked hi/lo)
  u64*      candbufT=(u64*)     carve((size_t)32*256*8);        //  0.07 MB
  unsigned* bar    = (unsigned*)carve(2048);
  // total ~103 MB of d_ws

  hipLaunchKernelGGL(prep_k, dim3(NB_CONV+NB_H0), dim3(256), 0, stream,
                     W_ih, W_hh, W_out, latent, W_lat, b_lat,
                     Wih_s, Whh_s, Wout_s, h_f32, h_seq, bar);
  hipLaunchKernelGGL(gitab_k, dim3(512), dim3(512), 0, stream, emb, Wih_s, gi_tab);

  void* kargs[] = {
    (void*)&Wout_s, (void*)&Whh_s, (void*)&gi_tab, (void*)&gh_buf, (void*)&h_f32,
    (void*)&h_seq, (void*)&candbufT, (void*)&b_ih, (void*)&b_hh, (void*)&b_out,
    (void*)&out, (void*)&bar
  };
  (void)hipLaunchCooperativeKernel((void*)decode_k, dim3(NBLK), dim3(512), kargs, 0, stream);
}

// Round 13
// 3119.980 us; speedup vs baseline: 1.1214x; 1.0206x over previous
//
#include <hip/hip_runtime.h>
#include <stdint.h>

// MoleculeDecoder r13: r8 (champion, 3083us) + ONE change: combine's gh loads
// hoisted above the candbuf gather (token-independent -> overlap L3 RTs).
// r9-r12 post-mortem: blocked ring / pair-combine / rootless barrier all
// netted 0 to -10% vs r8; reverting to r8 wholesale, single zero-risk tweak.

typedef unsigned long long u64;
typedef unsigned int u32;
typedef _Float16 f16;
using half8 = __attribute__((ext_vector_type(8))) _Float16;
using f32x4 = __attribute__((ext_vector_type(4))) float;
using uint4v = __attribute__((ext_vector_type(4))) unsigned int;

#define E_ 768
#define V_ 8192
#define T_ 256
#define HP 24576            // 32*768 (one h plane, elements)
#define IH_PLANE (2304*768)
#define OUT_PLANE (8192*768)
#define NBLK 256

#define AGENT_LD(p)    __hip_atomic_load((p), __ATOMIC_RELAXED, __HIP_MEMORY_SCOPE_AGENT)
#define AGENT_ST(p,v)  __hip_atomic_store((p), (v), __ATOMIC_RELAXED, __HIP_MEMORY_SCOPE_AGENT)
#define AGENT_ADD(p,v) __hip_atomic_fetch_add((p), (v), __ATOMIC_RELAXED, __HIP_MEMORY_SCOPE_AGENT)

__device__ __forceinline__ f32x4 mfma16(half8 a, half8 b, f32x4 c){
  return __builtin_amdgcn_mfma_f32_16x16x32_f16(a, b, c, 0, 0, 0);
}
__device__ __forceinline__ void split2(float f, f16& hi, f16& lo){
  f16 h = (f16)f; hi = h; lo = (f16)((f - (float)h) * 4096.0f);
}
__device__ __forceinline__ u32 packh(float f){
  f16 h, l; split2(f, h, l);
  return (u32)__builtin_bit_cast(unsigned short, h) |
         ((u32)__builtin_bit_cast(unsigned short, l) << 16);
}
__device__ __forceinline__ float unpackh(u32 u){
  f16 h = __builtin_bit_cast(f16, (unsigned short)(u & 0xffffu));
  f16 l = __builtin_bit_cast(f16, (unsigned short)(u >> 16));
  return (float)h + (float)l * (1.0f/4096.0f);
}
__device__ __forceinline__ u64 packkey(float f, int v){
  u32 fb = __float_as_uint(f);
  u32 s  = fb ^ ((u32)((int32_t)fb>>31) | 0x80000000u);
  return ((u64)s<<32) | (u64)(0xFFFFFFFFu - (u32)v);   // ties -> smaller idx wins
}

// ---------------- prep: split weights; h0 (f32 + packed ring slot 0); zero barrier ----------------
#define NB_CONV 1200
#define NB_H0   96
#define NG_IH   221184      // 2304*768/8
#define NG_ALL  1228800     // (2*2304 + 8192)*768/8

__global__ __launch_bounds__(256) void prep_k(
    const float* __restrict__ W_ih, const float* __restrict__ W_hh, const float* __restrict__ W_out,
    const float* __restrict__ latent, const float* __restrict__ W_lat, const float* __restrict__ b_lat,
    f16* __restrict__ Wih_s, f16* __restrict__ Whh_s, f16* __restrict__ Wout_s,
    float* __restrict__ h_f32, u32* __restrict__ h_seq, unsigned* __restrict__ bar)
{
  int blk = blockIdx.x;
  if (blk < NB_CONV){
    for (int g = blk*256 + threadIdx.x; g < NG_ALL; g += NB_CONV*256){
      const float* src; f16* hi; f16* lo; int off;
      if (g < NG_IH)        { src=W_ih; hi=Wih_s; lo=Wih_s+IH_PLANE; off=g*8; }
      else if (g < 2*NG_IH) { src=W_hh; hi=Whh_s; lo=Whh_s+IH_PLANE; off=(g-NG_IH)*8; }
      else                  { src=W_out; hi=Wout_s; lo=Wout_s+OUT_PLANE; off=(g-2*NG_IH)*8; }
      float4 a = *(const float4*)(src+off);
      float4 b = *(const float4*)(src+off+4);
      float fs[8] = {a.x,a.y,a.z,a.w,b.x,b.y,b.z,b.w};
      half8 vh, vl;
      #pragma unroll
      for (int j=0;j<8;j++){ f16 h,l; split2(fs[j],h,l); vh[j]=h; vl[j]=l; }
      *(half8*)(hi+off) = vh;
      *(half8*)(lo+off) = vl;
    }
  } else {
    if (blk==NB_CONV) bar[threadIdx.x] = 0;        // zero all barrier counters
    int tid = (blk-NB_CONV)*256 + threadIdx.x;     // 0..24575
    int b = tid/768, e = tid - b*768;
    const float4* wr = (const float4*)(W_lat + (size_t)e*768);
    const float4* xr = (const float4*)(latent + (size_t)b*768);
    float s0=0.f,s1=0.f,s2=0.f,s3=0.f;
    for (int k=0;k<192;k++){
      float4 w = wr[k]; float4 x = xr[k];
      s0 += w.x*x.x; s1 += w.y*x.y; s2 += w.z*x.z; s3 += w.w*x.w;
    }
    float acc = b_lat[e] + ((s0+s1)+(s2+s3));
    h_f32[b*768+e] = acc;
    h_seq[b*768+e] = packh(acc);                   // ring slot 0
  }
}

// ---------------- gi table: gi_tab[tok][2304] = packed(W_ih @ emb[tok]) ----------------
__global__ __launch_bounds__(512) void gitab_k(
    const float* __restrict__ emb, const f16* __restrict__ Wih_s, u32* __restrict__ gi_tab)
{
  __shared__ float red[3][8][2][64][4];
  const int bid = blockIdx.x, tid = threadIdx.x;
  const int tb = bid>>1, half = bid&1;
  const int w = tid>>6, lane = tid&63, col = lane&15, kg = lane>>4, kc = w;
  half8 ah[2][3], al[2][3];
  #pragma unroll
  for (int m=0;m<2;m++)
    #pragma unroll
    for (int i=0;i<3;i++){
      const float* src = emb + (size_t)(tb*32 + m*16 + col)*768 + kc*96 + i*32 + kg*8;
      float4 x0 = *(const float4*)src, x1 = *(const float4*)(src+4);
      float fs[8] = {x0.x,x0.y,x0.z,x0.w,x1.x,x1.y,x1.z,x1.w};
      half8 vh, vl;
      #pragma unroll
      for (int j=0;j<8;j++){ f16 h,l; split2(fs[j],h,l); vh[j]=h; vl[j]=l; }
      ah[m][i]=vh; al[m][i]=vl;
    }
  for (int g=0; g<24; ++g){
    #pragma unroll
    for (int j=0;j<3;j++){
      const int nt = half*72 + g*3 + j;
      f32x4 a0[2], a1[2];
      #pragma unroll
      for (int m=0;m<2;m++){ a0[m]=f32x4{0,0,0,0}; a1[m]=f32x4{0,0,0,0}; }
      #pragma unroll
      for (int i=0;i<3;i++){
        size_t o = (size_t)(nt*16+col)*768 + kc*96 + i*32 + kg*8;
        half8 bh = *(const half8*)(Wih_s + o);
        half8 bl = *(const half8*)(Wih_s + IH_PLANE + o);
        #pragma unroll
        for (int m=0;m<2;m++){
          a0[m] = mfma16(ah[m][i], bh, a0[m]);
          a1[m] = mfma16(ah[m][i], bl, a1[m]);
          a1[m] = mfma16(al[m][i], bh, a1[m]);
        }
      }
      #pragma unroll
      for (int m=0;m<2;m++){
        f32x4 v;
        #pragma unroll
        for (int r=0;r<4;r++) v[r] = a0[m][r] + a1[m][r]*(1.0f/4096.0f);
        *(f32x4*)&red[j][w][m][lane][0] = v;
      }
    }
    __syncthreads();
    if (w < 6){
      const int j = w>>1, m = w&1;
      f32x4 s = {0,0,0,0};
      #pragma unroll
      for (int ww=0; ww<8; ww++) s += *(const f32x4*)&red[j][ww][m][lane][0];
      const int nt = half*72 + g*3 + j;
      const int tokr = tb*32 + m*16 + kg*4;
      #pragma unroll
      for (int r=0;r<4;r++)
        gi_tab[(size_t)(tokr+r)*2304 + nt*16 + col] = packh(s[r]);
    }
    __syncthreads();
  }
}

// ---------------- grid barrier: two-level tree, relaxed coherent, no fences ----------------
__device__ __forceinline__ void gridbar(unsigned* bar, unsigned target){
  __syncthreads();   // drains each wave's vmem ops (sc1 stores now globally visible)
  if (threadIdx.x == 0){
    const int g = blockIdx.x & 7;
    unsigned old = AGENT_ADD(&bar[g*16], 1u);
    if (old == 32u*target - 1u)
      AGENT_ADD(&bar[128], 1u);
    int spins = 0;
    while (AGENT_LD(&bar[128]) < 8u*target){
      __builtin_amdgcn_s_sleep(1);
      if ((++spins & 2047) == 0)
        AGENT_ADD(&bar[128], 0u);
    }
  }
  __syncthreads();
}

// ---------------- persistent decode kernel (cooperative, 256 x 512) ----------------
__global__ __launch_bounds__(512, 2) void decode_k(
    const f16* __restrict__ Wout_s, const f16* __restrict__ Whh_s, const u32* __restrict__ gi_tab,
    float* __restrict__ gh_buf, const float* __restrict__ h_f32, u32* __restrict__ h_seq,
    u64* __restrict__ candbufT, const float* __restrict__ b_ih, const float* __restrict__ b_hh,
    const float* __restrict__ b_out, float* __restrict__ out, unsigned* __restrict__ bar)
{
  __shared__ float red[3][8][2][64][4];   // 48 KB
  __shared__ u64 amkey[32];
  const int bid = blockIdx.x, tid = threadIdx.x;
  const int w = tid>>6, lane = tid&63, col = lane&15, kg = lane>>4, kc = w;

  // One-time L2/L1 invalidate: kill any stale (poison) lines before cached h reads.
  __builtin_amdgcn_fence(__ATOMIC_ACQUIRE, "agent");
  __syncthreads();

  // ---- persistent B fragments (held in VGPRs for the whole kernel) ----
  const f16* srcH[3] = {Wout_s, Wout_s, (bid<144)? Whh_s : Wout_s};
  const f16* srcL[3] = {Wout_s+OUT_PLANE, Wout_s+OUT_PLANE,
                        (bid<144)? Whh_s+IH_PLANE : Wout_s+OUT_PLANE};
  const int  rowb[3] = {bid*16, 4096+bid*16, (bid<144)? bid*16 : 0};
  half8 bf_h[3][3], bf_l[3][3];
  #pragma unroll
  for (int s=0;s<3;s++)
    #pragma unroll
    for (int i=0;i<3;i++){
      size_t o = (size_t)(rowb[s]+col)*768 + kc*96 + i*32 + kg*8;
      bf_h[s][i] = *(const half8*)(srcH[s] + o);
      bf_l[s][i] = *(const half8*)(srcL[s] + o);
    }
  float bo_reg[2];
  bo_reg[0] = b_out[bid*16 + col];
  bo_reg[1] = b_out[4096 + bid*16 + col];

  // combine-role hoists (blocks 0..47 own h elements)
  int cb = 0, ce = 0; float hreg = 0.f;
  float bir=0,biz=0,bin_=0,bhr=0,bhz=0,bhn=0;
  if (bid < 48){
    int gid = bid*512 + tid;
    cb = gid/768; ce = gid - cb*768;
    hreg = h_f32[cb*768 + ce];
    bir=b_ih[ce]; biz=b_ih[768+ce]; bin_=b_ih[1536+ce];
    bhr=b_hh[ce]; bhz=b_hh[768+ce]; bhn=b_hh[1536+ce];
  }

  unsigned bt = 0;
  for (int t=0; t<=256; ++t){
    // =================== phase A ===================
    if (tid < 32) amkey[tid] = 0;
    // A-frags: NORMAL CACHED wide loads from this step's ring slot (fresh
    // addresses each step -> no stale-L2 hazard; per-XCD L2 merges the 32
    // resident blocks' misses so L3 serves each line ~8x, not 256x).
    const u32* hbase = h_seq + (size_t)t*HP;
    uint4v qa[2][3], qb[2][3];
    #pragma unroll
    for (int m=0;m<2;m++)
      #pragma unroll
      for (int i=0;i<3;i++){
        const uint4v* hp = (const uint4v*)(hbase + (m*16+col)*768 + kc*96 + i*32 + kg*8);
        qa[m][i] = hp[0];
        qb[m][i] = hp[1];
      }
    half8 ah[2][3], al[2][3];
    #pragma unroll
    for (int m=0;m<2;m++)
      #pragma unroll
      for (int i=0;i<3;i++){
        uint4v wh, wl;
        u32 d[8] = {qa[m][i][0],qa[m][i][1],qa[m][i][2],qa[m][i][3],
                    qb[m][i][0],qb[m][i][1],qb[m][i][2],qb[m][i][3]};
        #pragma unroll
        for (int j=0;j<4;j++){
          u32 w0 = d[2*j], w1 = d[2*j+1];
          wh[j] = (w0 & 0xffffu) | (w1 << 16);
          wl[j] = (w0 >> 16) | (w1 & 0xffff0000u);
        }
        ah[m][i] = __builtin_bit_cast(half8, wh);
        al[m][i] = __builtin_bit_cast(half8, wl);
      }
    #pragma unroll
    for (int s=0;s<3;s++){
      f32x4 a0[2], a1[2];
      #pragma unroll
      for (int m=0;m<2;m++){ a0[m]=f32x4{0,0,0,0}; a1[m]=f32x4{0,0,0,0}; }
      #pragma unroll
      for (int i=0;i<3;i++)
        #pragma unroll
        for (int m=0;m<2;m++){
          a0[m] = mfma16(ah[m][i], bf_h[s][i], a0[m]);
          a1[m] = mfma16(ah[m][i], bf_l[s][i], a1[m]);
          a1[m] = mfma16(al[m][i], bf_h[s][i], a1[m]);
        }
      #pragma unroll
      for (int m=0;m<2;m++){
        f32x4 v;
        #pragma unroll
        for (int r=0;r<4;r++) v[r] = a0[m][r] + a1[m][r]*(1.0f/4096.0f);
        *(f32x4*)&red[s][w][m][lane][0] = v;
      }
    }
    __syncthreads();
    float sv[2][4];                       // deferred logit stores (cross-barrier)
    bool have_out = false;
    if (w < 3){
      const int s = w;
      float vm[2][4];
      #pragma unroll
      for (int m=0;m<2;m++){
        f32x4 sum = {0,0,0,0};
        #pragma unroll
        for (int ww=0; ww<8; ww++) sum += *(const f32x4*)&red[s][ww][m][lane][0];
        #pragma unroll
        for (int r=0;r<4;r++) vm[m][r] = sum[r];
      }
      if (s < 2){
        if (t >= 1){
          have_out = true;
          const int v = s*4096 + bid*16 + col;
          const float bo = bo_reg[s];
          #pragma unroll
          for (int m=0;m<2;m++)
            #pragma unroll
            for (int r=0;r<4;r++){
              const int b = m*16 + kg*4 + r;
              const float p = vm[m][r] + bo;
              sv[m][r] = p;
              u64 key = packkey(p, v);
              #pragma unroll
              for (int off=1; off<16; off<<=1){
                u64 o = __shfl_xor((unsigned long long)key, off);
                if (o > key) key = o;
              }
              if (col == 0) atomicMax(&amkey[b], key);
            }
        }
      } else if (bid < 144){
        const int gr = bid*16 + col;
        #pragma unroll
        for (int m=0;m<2;m++)
          #pragma unroll
          for (int r=0;r<4;r++)
            AGENT_ST(&gh_buf[(m*16+kg*4+r)*2304 + gr], vm[m][r]);
      }
    }
    __syncthreads();                      // amkey final
    // transposed candbuf: writer scatters 32 x 8B (uncontended), reader coalesced
    if (t >= 1 && tid < 32) AGENT_ST(&candbufT[(size_t)tid*256 + bid], amkey[tid]);
    if (t == 256){                        // last step: store logits, done
      if (have_out){
        const int v = w*4096 + bid*16 + col;
        #pragma unroll
        for (int m=0;m<2;m++)
          #pragma unroll
          for (int r=0;r<4;r++)
            out[(size_t)(m*16+kg*4+r)*((size_t)T_*V_) + (size_t)(t-1)*V_ + v] = sv[m][r];
      }
      break;
    }
    gridbar(bar, ++bt);
    // =================== out stores (off barrier-arrival path) + phase B ===================
    if (bid >= 48){
      if (have_out){
        const int v = w*4096 + bid*16 + col;
        #pragma unroll
        for (int m=0;m<2;m++)
          #pragma unroll
          for (int r=0;r<4;r++)
            out[(size_t)(m*16+kg*4+r)*((size_t)T_*V_) + (size_t)(t-1)*V_ + v] = sv[m][r];
      }
    } else {
      // EARLY ISSUE (r13's only change vs r8): gh loads are token-independent,
      // so fire them before the candbuf gather — their L3 latency overlaps the
      // gather round-trip instead of serializing after it.
      float* hb = gh_buf + cb*2304 + ce;
      const float ghr0 = AGENT_LD(hb);
      const float ghz0 = AGENT_LD(hb + 768);
      const float ghn0 = AGENT_LD(hb + 1536);
      int tok = 1;
      if (t > 0){
        u64 k = 0;
        #pragma unroll
        for (int j=0;j<4;j++){
          u64 c = AGENT_LD(&candbufT[(size_t)cb*256 + lane + 64*j]);
          if (c > k) k = c;
        }
        #pragma unroll
        for (int off=1; off<64; off<<=1){
          u64 o = __shfl_xor((unsigned long long)k, off);
          if (o > k) k = o;
        }
        tok = (int)(0xFFFFFFFFu - (unsigned)(k & 0xFFFFFFFFull));
      }
      const u32* gp = gi_tab + (size_t)tok*2304 + ce;   // plain cached loads (read-only)
      const float gir = unpackh(gp[0])    + bir;
      const float giz = unpackh(gp[768])  + biz;
      const float gin = unpackh(gp[1536]) + bin_;
      const float ghr = ghr0 + bhr;
      const float ghz = ghz0 + bhz;
      const float ghn = ghn0 + bhn;
      const float rr = 1.0f/(1.0f+expf(-(gir+ghr)));
      const float zz = 1.0f/(1.0f+expf(-(giz+ghz)));
      const float nn = tanhf(gin + rr*ghn);
      hreg = (1.0f-zz)*nn + zz*hreg;
      AGENT_ST(&h_seq[(size_t)(t+1)*HP + cb*768 + ce], packh(hreg));  // next ring slot
      if (have_out){                       // after h store: off gi-load path
        const int v = w*4096 + bid*16 + col;
        #pragma unroll
        for (int m=0;m<2;m++)
          #pragma unroll
          for (int r=0;r<4;r++)
            out[(size_t)(m*16+kg*4+r)*((size_t)T_*V_) + (size_t)(t-1)*V_ + v] = sv[m][r];
      }
    }
    gridbar(bar, ++bt);
  }
}

// ---------------- host ----------------
extern "C" void kernel_launch(void* const* d_in, const int* in_sizes, int n_in,
                              void* d_out, int out_size, void* d_ws, size_t ws_size,
                              hipStream_t stream){
  const float* latent = (const float*)d_in[0];
  const float* W_lat  = (const float*)d_in[1];
  const float* b_lat  = (const float*)d_in[2];
  const float* emb    = (const float*)d_in[3];
  const float* W_ih   = (const float*)d_in[4];
  const float* W_hh   = (const float*)d_in[5];
  const float* b_ih   = (const float*)d_in[6];
  const float* b_hh   = (const float*)d_in[7];
  const float* W_out  = (const float*)d_in[8];
  const float* b_out  = (const float*)d_in[9];
  float* out = (float*)d_out;
  (void)in_sizes; (void)n_in; (void)out_size; (void)ws_size;

  char* ws = (char*)d_ws;
  size_t off = 0;
  auto carve = [&](size_t bytes)->char*{
    char* p = ws + off; off += (bytes + 255) & ~(size_t)255; return p;
  };
  f16*      Wih_s  = (f16*)     carve((size_t)2*IH_PLANE*2);    //  7.08 MB
  f16*      Whh_s  = (f16*)     carve((size_t)2*IH_PLANE*2);    //  7.08 MB
  f16*      Wout_s = (f16*)     carve((size_t)2*OUT_PLANE*2);   // 25.17 MB
  u32*      gi_tab = (u32*)     carve((size_t)8192*2304*4);     // 37.75 MB (packed)
  float*    gh_buf = (float*)   carve((size_t)32*2304*4);       //  0.29 MB
  float*    h_f32  = (float*)   carve((size_t)HP*4);            //  0.10 MB
  u32*      h_seq  = (u32*)     carve((size_t)257*HP*4);        // 25.26 MB ring
  u64*      candbufT=(u64*)     carve((size_t)32*256*8);        //  0.07 MB
  unsigned* bar    = (unsigned*)carve(2048);
  // total ~103 MB of d_ws

  hipLaunchKernelGGL(prep_k, dim3(NB_CONV+NB_H0), dim3(256), 0, stream,
                     W_ih, W_hh, W_out, latent, W_lat, b_lat,
                     Wih_s, Whh_s, Wout_s, h_f32, h_seq, bar);
  hipLaunchKernelGGL(gitab_k, dim3(512), dim3(512), 0, stream, emb, Wih_s, gi_tab);

  void* kargs[] = {
    (void*)&Wout_s, (void*)&Whh_s, (void*)&gi_tab, (void*)&gh_buf, (void*)&h_f32,
    (void*)&h_seq, (void*)&candbufT, (void*)&b_ih, (void*)&b_hh, (void*)&b_out,
    (void*)&out, (void*)&bar
  };
  (void)hipLaunchCooperativeKernel((void*)decode_k, dim3(NBLK), dim3(512), kargs, 0, stream);
}

// Round 14
// 3113.684 us; speedup vs baseline: 1.1237x; 1.0020x over previous
//
#include <hip/hip_runtime.h>
#include <stdint.h>

// MoleculeDecoder r14: r13 + ASYMMETRIC barriers.
// bar1 (pa done): arrive by ALL 256, waited on ONLY by the 48 combine blocks.
// bar2 (h ready): arrive by ONLY the 48 combine blocks, waited on by ALL.
// Rationale: barrier participation should match the dependency graph —
// removes 208 blocks' bar1 detect round, cuts bar2 arrive RMWs 256->48, and
// moves combine's out-stores after its bar2 arrive (off the release edge).

typedef unsigned long long u64;
typedef unsigned int u32;
typedef _Float16 f16;
using half8 = __attribute__((ext_vector_type(8))) _Float16;
using f32x4 = __attribute__((ext_vector_type(4))) float;
using uint4v = __attribute__((ext_vector_type(4))) unsigned int;

#define E_ 768
#define V_ 8192
#define T_ 256
#define HP 24576            // 32*768 (one h plane, elements)
#define IH_PLANE (2304*768)
#define OUT_PLANE (8192*768)
#define NBLK 256

#define AGENT_LD(p)    __hip_atomic_load((p), __ATOMIC_RELAXED, __HIP_MEMORY_SCOPE_AGENT)
#define AGENT_ST(p,v)  __hip_atomic_store((p), (v), __ATOMIC_RELAXED, __HIP_MEMORY_SCOPE_AGENT)
#define AGENT_ADD(p,v) __hip_atomic_fetch_add((p), (v), __ATOMIC_RELAXED, __HIP_MEMORY_SCOPE_AGENT)

__device__ __forceinline__ f32x4 mfma16(half8 a, half8 b, f32x4 c){
  return __builtin_amdgcn_mfma_f32_16x16x32_f16(a, b, c, 0, 0, 0);
}
__device__ __forceinline__ void split2(float f, f16& hi, f16& lo){
  f16 h = (f16)f; hi = h; lo = (f16)((f - (float)h) * 4096.0f);
}
__device__ __forceinline__ u32 packh(float f){
  f16 h, l; split2(f, h, l);
  return (u32)__builtin_bit_cast(unsigned short, h) |
         ((u32)__builtin_bit_cast(unsigned short, l) << 16);
}
__device__ __forceinline__ float unpackh(u32 u){
  f16 h = __builtin_bit_cast(f16, (unsigned short)(u & 0xffffu));
  f16 l = __builtin_bit_cast(f16, (unsigned short)(u >> 16));
  return (float)h + (float)l * (1.0f/4096.0f);
}
__device__ __forceinline__ u64 packkey(float f, int v){
  u32 fb = __float_as_uint(f);
  u32 s  = fb ^ ((u32)((int32_t)fb>>31) | 0x80000000u);
  return ((u64)s<<32) | (u64)(0xFFFFFFFFu - (u32)v);   // ties -> smaller idx wins
}

// ---------------- prep: split weights; h0 (f32 + packed ring slot 0); zero barriers ----------------
#define NB_CONV 1200
#define NB_H0   96
#define NG_IH   221184      // 2304*768/8
#define NG_ALL  1228800     // (2*2304 + 8192)*768/8

__global__ __launch_bounds__(256) void prep_k(
    const float* __restrict__ W_ih, const float* __restrict__ W_hh, const float* __restrict__ W_out,
    const float* __restrict__ latent, const float* __restrict__ W_lat, const float* __restrict__ b_lat,
    f16* __restrict__ Wih_s, f16* __restrict__ Whh_s, f16* __restrict__ Wout_s,
    float* __restrict__ h_f32, u32* __restrict__ h_seq, unsigned* __restrict__ bar)
{
  int blk = blockIdx.x;
  if (blk < NB_CONV){
    for (int g = blk*256 + threadIdx.x; g < NG_ALL; g += NB_CONV*256){
      const float* src; f16* hi; f16* lo; int off;
      if (g < NG_IH)        { src=W_ih; hi=Wih_s; lo=Wih_s+IH_PLANE; off=g*8; }
      else if (g < 2*NG_IH) { src=W_hh; hi=Whh_s; lo=Whh_s+IH_PLANE; off=(g-NG_IH)*8; }
      else                  { src=W_out; hi=Wout_s; lo=Wout_s+OUT_PLANE; off=(g-2*NG_IH)*8; }
      float4 a = *(const float4*)(src+off);
      float4 b = *(const float4*)(src+off+4);
      float fs[8] = {a.x,a.y,a.z,a.w,b.x,b.y,b.z,b.w};
      half8 vh, vl;
      #pragma unroll
      for (int j=0;j<8;j++){ f16 h,l; split2(fs[j],h,l); vh[j]=h; vl[j]=l; }
      *(half8*)(hi+off) = vh;
      *(half8*)(lo+off) = vl;
    }
  } else {
    if (blk==NB_CONV){ bar[threadIdx.x] = 0; bar[256+threadIdx.x] = 0; }
    int tid = (blk-NB_CONV)*256 + threadIdx.x;     // 0..24575
    int b = tid/768, e = tid - b*768;
    const float4* wr = (const float4*)(W_lat + (size_t)e*768);
    const float4* xr = (const float4*)(latent + (size_t)b*768);
    float s0=0.f,s1=0.f,s2=0.f,s3=0.f;
    for (int k=0;k<192;k++){
      float4 w = wr[k]; float4 x = xr[k];
      s0 += w.x*x.x; s1 += w.y*x.y; s2 += w.z*x.z; s3 += w.w*x.w;
    }
    float acc = b_lat[e] + ((s0+s1)+(s2+s3));
    h_f32[b*768+e] = acc;
    h_seq[b*768+e] = packh(acc);                   // ring slot 0
  }
}

// ---------------- gi table: gi_tab[tok][2304] = packed(W_ih @ emb[tok]) ----------------
__global__ __launch_bounds__(512) void gitab_k(
    const float* __restrict__ emb, const f16* __restrict__ Wih_s, u32* __restrict__ gi_tab)
{
  __shared__ float red[3][8][2][64][4];
  const int bid = blockIdx.x, tid = threadIdx.x;
  const int tb = bid>>1, half = bid&1;
  const int w = tid>>6, lane = tid&63, col = lane&15, kg = lane>>4, kc = w;
  half8 ah[2][3], al[2][3];
  #pragma unroll
  for (int m=0;m<2;m++)
    #pragma unroll
    for (int i=0;i<3;i++){
      const float* src = emb + (size_t)(tb*32 + m*16 + col)*768 + kc*96 + i*32 + kg*8;
      float4 x0 = *(const float4*)src, x1 = *(const float4*)(src+4);
      float fs[8] = {x0.x,x0.y,x0.z,x0.w,x1.x,x1.y,x1.z,x1.w};
      half8 vh, vl;
      #pragma unroll
      for (int j=0;j<8;j++){ f16 h,l; split2(fs[j],h,l); vh[j]=h; vl[j]=l; }
      ah[m][i]=vh; al[m][i]=vl;
    }
  for (int g=0; g<24; ++g){
    #pragma unroll
    for (int j=0;j<3;j++){
      const int nt = half*72 + g*3 + j;
      f32x4 a0[2], a1[2];
      #pragma unroll
      for (int m=0;m<2;m++){ a0[m]=f32x4{0,0,0,0}; a1[m]=f32x4{0,0,0,0}; }
      #pragma unroll
      for (int i=0;i<3;i++){
        size_t o = (size_t)(nt*16+col)*768 + kc*96 + i*32 + kg*8;
        half8 bh = *(const half8*)(Wih_s + o);
        half8 bl = *(const half8*)(Wih_s + IH_PLANE + o);
        #pragma unroll
        for (int m=0;m<2;m++){
          a0[m] = mfma16(ah[m][i], bh, a0[m]);
          a1[m] = mfma16(ah[m][i], bl, a1[m]);
          a1[m] = mfma16(al[m][i], bh, a1[m]);
        }
      }
      #pragma unroll
      for (int m=0;m<2;m++){
        f32x4 v;
        #pragma unroll
        for (int r=0;r<4;r++) v[r] = a0[m][r] + a1[m][r]*(1.0f/4096.0f);
        *(f32x4*)&red[j][w][m][lane][0] = v;
      }
    }
    __syncthreads();
    if (w < 6){
      const int j = w>>1, m = w&1;
      f32x4 s = {0,0,0,0};
      #pragma unroll
      for (int ww=0; ww<8; ww++) s += *(const f32x4*)&red[j][ww][m][lane][0];
      const int nt = half*72 + g*3 + j;
      const int tokr = tb*32 + m*16 + kg*4;
      #pragma unroll
      for (int r=0;r<4;r++)
        gi_tab[(size_t)(tokr+r)*2304 + nt*16 + col] = packh(s[r]);
    }
    __syncthreads();
  }
}

// ---------------- poll helper: single root line, relaxed, RMW insurance ----------------
__device__ __forceinline__ void pollroot(unsigned* p, u32 goal){
  int spins = 0;
  while (AGENT_LD(p) < goal){
    __builtin_amdgcn_s_sleep(1);
    if ((++spins & 2047) == 0) AGENT_ADD(p, 0u);
  }
}

// ---------------- persistent decode kernel (cooperative, 256 x 512) ----------------
// bar layout: bar1 groups [g*16] g=0..7, root1 [128];
//             bar2 groups [192+g*16] g=0..7, root2 [320].
__global__ __launch_bounds__(512, 2) void decode_k(
    const f16* __restrict__ Wout_s, const f16* __restrict__ Whh_s, const u32* __restrict__ gi_tab,
    float* __restrict__ gh_buf, const float* __restrict__ h_f32, u32* __restrict__ h_seq,
    u64* __restrict__ candbufT, const float* __restrict__ b_ih, const float* __restrict__ b_hh,
    const float* __restrict__ b_out, float* __restrict__ out, unsigned* __restrict__ bar)
{
  __shared__ float red[3][8][2][64][4];   // 48 KB
  __shared__ u64 amkey[32];
  const int bid = blockIdx.x, tid = threadIdx.x;
  const int w = tid>>6, lane = tid&63, col = lane&15, kg = lane>>4, kc = w;

  // One-time L2/L1 invalidate: kill any stale (poison) lines before cached h reads.
  __builtin_amdgcn_fence(__ATOMIC_ACQUIRE, "agent");
  __syncthreads();

  // ---- persistent B fragments (held in VGPRs for the whole kernel) ----
  const f16* srcH[3] = {Wout_s, Wout_s, (bid<144)? Whh_s : Wout_s};
  const f16* srcL[3] = {Wout_s+OUT_PLANE, Wout_s+OUT_PLANE,
                        (bid<144)? Whh_s+IH_PLANE : Wout_s+OUT_PLANE};
  const int  rowb[3] = {bid*16, 4096+bid*16, (bid<144)? bid*16 : 0};
  half8 bf_h[3][3], bf_l[3][3];
  #pragma unroll
  for (int s=0;s<3;s++)
    #pragma unroll
    for (int i=0;i<3;i++){
      size_t o = (size_t)(rowb[s]+col)*768 + kc*96 + i*32 + kg*8;
      bf_h[s][i] = *(const half8*)(srcH[s] + o);
      bf_l[s][i] = *(const half8*)(srcL[s] + o);
    }
  float bo_reg[2];
  bo_reg[0] = b_out[bid*16 + col];
  bo_reg[1] = b_out[4096 + bid*16 + col];

  // combine-role hoists (blocks 0..47 own h elements)
  int cb = 0, ce = 0; float hreg = 0.f;
  float bir=0,biz=0,bin_=0,bhr=0,bhz=0,bhn=0;
  if (bid < 48){
    int gid = bid*512 + tid;
    cb = gid/768; ce = gid - cb*768;
    hreg = h_f32[cb*768 + ce];
    bir=b_ih[ce]; biz=b_ih[768+ce]; bin_=b_ih[1536+ce];
    bhr=b_hh[ce]; bhz=b_hh[768+ce]; bhn=b_hh[1536+ce];
  }

  for (int t=0; t<=256; ++t){
    // =================== phase A ===================
    if (tid < 32) amkey[tid] = 0;
    const u32* hbase = h_seq + (size_t)t*HP;
    uint4v qa[2][3], qb[2][3];
    #pragma unroll
    for (int m=0;m<2;m++)
      #pragma unroll
      for (int i=0;i<3;i++){
        const uint4v* hp = (const uint4v*)(hbase + (m*16+col)*768 + kc*96 + i*32 + kg*8);
        qa[m][i] = hp[0];
        qb[m][i] = hp[1];
      }
    half8 ah[2][3], al[2][3];
    #pragma unroll
    for (int m=0;m<2;m++)
      #pragma unroll
      for (int i=0;i<3;i++){
        uint4v wh, wl;
        u32 d[8] = {qa[m][i][0],qa[m][i][1],qa[m][i][2],qa[m][i][3],
                    qb[m][i][0],qb[m][i][1],qb[m][i][2],qb[m][i][3]};
        #pragma unroll
        for (int j=0;j<4;j++){
          u32 w0 = d[2*j], w1 = d[2*j+1];
          wh[j] = (w0 & 0xffffu) | (w1 << 16);
          wl[j] = (w0 >> 16) | (w1 & 0xffff0000u);
        }
        ah[m][i] = __builtin_bit_cast(half8, wh);
        al[m][i] = __builtin_bit_cast(half8, wl);
      }
    #pragma unroll
    for (int s=0;s<3;s++){
      f32x4 a0[2], a1[2];
      #pragma unroll
      for (int m=0;m<2;m++){ a0[m]=f32x4{0,0,0,0}; a1[m]=f32x4{0,0,0,0}; }
      #pragma unroll
      for (int i=0;i<3;i++)
        #pragma unroll
        for (int m=0;m<2;m++){
          a0[m] = mfma16(ah[m][i], bf_h[s][i], a0[m]);
          a1[m] = mfma16(ah[m][i], bf_l[s][i], a1[m]);
          a1[m] = mfma16(al[m][i], bf_h[s][i], a1[m]);
        }
      #pragma unroll
      for (int m=0;m<2;m++){
        f32x4 v;
        #pragma unroll
        for (int r=0;r<4;r++) v[r] = a0[m][r] + a1[m][r]*(1.0f/4096.0f);
        *(f32x4*)&red[s][w][m][lane][0] = v;
      }
    }
    __syncthreads();
    float sv[2][4];                       // deferred logit stores
    bool have_out = false;
    if (w < 3){
      const int s = w;
      float vm[2][4];
      #pragma unroll
      for (int m=0;m<2;m++){
        f32x4 sum = {0,0,0,0};
        #pragma unroll
        for (int ww=0; ww<8; ww++) sum += *(const f32x4*)&red[s][ww][m][lane][0];
        #pragma unroll
        for (int r=0;r<4;r++) vm[m][r] = sum[r];
      }
      if (s < 2){
        if (t >= 1){
          have_out = true;
          const int v = s*4096 + bid*16 + col;
          const float bo = bo_reg[s];
          #pragma unroll
          for (int m=0;m<2;m++)
            #pragma unroll
            for (int r=0;r<4;r++){
              const int b = m*16 + kg*4 + r;
              const float p = vm[m][r] + bo;
              sv[m][r] = p;
              u64 key = packkey(p, v);
              #pragma unroll
              for (int off=1; off<16; off<<=1){
                u64 o = __shfl_xor((unsigned long long)key, off);
                if (o > key) key = o;
              }
              if (col == 0) atomicMax(&amkey[b], key);
            }
        }
      } else if (bid < 144){
        const int gr = bid*16 + col;
        #pragma unroll
        for (int m=0;m<2;m++)
          #pragma unroll
          for (int r=0;r<4;r++)
            AGENT_ST(&gh_buf[(m*16+kg*4+r)*2304 + gr], vm[m][r]);
      }
    }
    __syncthreads();                      // amkey final
    if (t >= 1 && tid < 32) AGENT_ST(&candbufT[(size_t)tid*256 + bid], amkey[tid]);
    if (t == 256){                        // last step: store logits, done
      if (have_out){
        const int v = w*4096 + bid*16 + col;
        #pragma unroll
        for (int m=0;m<2;m++)
          #pragma unroll
          for (int r=0;r<4;r++)
            out[(size_t)(m*16+kg*4+r)*((size_t)T_*V_) + (size_t)(t-1)*V_ + v] = sv[m][r];
      }
      break;
    }
    const u32 stp = (u32)(t+1);
    // ---- bar1: ALL arrive; only combine blocks wait ----
    __syncthreads();                      // drain candbuf/gh stores (all waves)
    if (tid == 0){
      unsigned old = AGENT_ADD(&bar[(bid&7)*16], 1u);
      if (old == 32u*stp - 1u) AGENT_ADD(&bar[128], 1u);
    }
    if (bid < 48){
      if (tid == 0) pollroot(&bar[128], 8u*stp);
      __syncthreads();
      // phase B: gh early (token-independent), gather, gi, GRU, h store
      float* hb = gh_buf + cb*2304 + ce;
      const float ghr0 = AGENT_LD(hb);
      const float ghz0 = AGENT_LD(hb + 768);
      const float ghn0 = AGENT_LD(hb + 1536);
      int tok = 1;
      if (t > 0){
        u64 k = 0;
        #pragma unroll
        for (int j=0;j<4;j++){
          u64 c = AGENT_LD(&candbufT[(size_t)cb*256 + lane + 64*j]);
          if (c > k) k = c;
        }
        #pragma unroll
        for (int off=1; off<64; off<<=1){
          u64 o = __shfl_xor((unsigned long long)k, off);
          if (o > k) k = o;
        }
        tok = (int)(0xFFFFFFFFu - (unsigned)(k & 0xFFFFFFFFull));
      }
      const u32* gp = gi_tab + (size_t)tok*2304 + ce;
      const float gir = unpackh(gp[0])    + bir;
      const float giz = unpackh(gp[768])  + biz;
      const float gin = unpackh(gp[1536]) + bin_;
      const float ghr = ghr0 + bhr;
      const float ghz = ghz0 + bhz;
      const float ghn = ghn0 + bhn;
      const float rr = 1.0f/(1.0f+expf(-(gir+ghr)));
      const float zz = 1.0f/(1.0f+expf(-(giz+ghz)));
      const float nn = tanhf(gin + rr*ghn);
      hreg = (1.0f-zz)*nn + zz*hreg;
      AGENT_ST(&h_seq[(size_t)(t+1)*HP + cb*768 + ce], packh(hreg));
      __syncthreads();                    // drain h stores (all waves)
      if (tid == 0){
        unsigned old = AGENT_ADD(&bar[192 + (bid&7)*16], 1u);
        if (old == 6u*stp - 1u) AGENT_ADD(&bar[320], 1u);
      }
      if (have_out){                      // after arrive: off the release edge
        const int v = w*4096 + bid*16 + col;
        #pragma unroll
        for (int m=0;m<2;m++)
          #pragma unroll
          for (int r=0;r<4;r++)
            out[(size_t)(m*16+kg*4+r)*((size_t)T_*V_) + (size_t)(t-1)*V_ + v] = sv[m][r];
      }
    } else {
      if (have_out){                      // overlaps combine entirely
        const int v = w*4096 + bid*16 + col;
        #pragma unroll
        for (int m=0;m<2;m++)
          #pragma unroll
          for (int r=0;r<4;r++)
            out[(size_t)(m*16+kg*4+r)*((size_t)T_*V_) + (size_t)(t-1)*V_ + v] = sv[m][r];
      }
    }
    // ---- bar2 (h ready): everyone waits on root2 ----
    if (tid == 0) pollroot(&bar[320], 8u*stp);
    __syncthreads();
  }
}

// ---------------- host ----------------
extern "C" void kernel_launch(void* const* d_in, const int* in_sizes, int n_in,
                              void* d_out, int out_size, void* d_ws, size_t ws_size,
                              hipStream_t stream){
  const float* latent = (const float*)d_in[0];
  const float* W_lat  = (const float*)d_in[1];
  const float* b_lat  = (const float*)d_in[2];
  const float* emb    = (const float*)d_in[3];
  const float* W_ih   = (const float*)d_in[4];
  const float* W_hh   = (const float*)d_in[5];
  const float* b_ih   = (const float*)d_in[6];
  const float* b_hh   = (const float*)d_in[7];
  const float* W_out  = (const float*)d_in[8];
  const float* b_out  = (const float*)d_in[9];
  float* out = (float*)d_out;
  (void)in_sizes; (void)n_in; (void)out_size; (void)ws_size;

  char* ws = (char*)d_ws;
  size_t off = 0;
  auto carve = [&](size_t bytes)->char*{
    char* p = ws + off; off += (bytes + 255) & ~(size_t)255; return p;
  };
  f16*      Wih_s  = (f16*)     carve((size_t)2*IH_PLANE*2);    //  7.08 MB
  f16*      Whh_s  = (f16*)     carve((size_t)2*IH_PLANE*2);    //  7.08 MB
  f16*      Wout_s = (f16*)     carve((size_t)2*OUT_PLANE*2);   // 25.17 MB
  u32*      gi_tab = (u32*)     carve((size_t)8192*2304*4);     // 37.75 MB (packed)
  float*    gh_buf = (float*)   carve((size_t)32*2304*4);       //  0.29 MB
  float*    h_f32  = (float*)   carve((size_t)HP*4);            //  0.10 MB
  u32*      h_seq  = (u32*)     carve((size_t)257*HP*4);        // 25.26 MB ring
  u64*      candbufT=(u64*)     carve((size_t)32*256*8);        //  0.07 MB
  unsigned* bar    = (unsigned*)carve(2048);
  // total ~103 MB of d_ws

  hipLaunchKernelGGL(prep_k, dim3(NB_CONV+NB_H0), dim3(256), 0, stream,
                     W_ih, W_hh, W_out, latent, W_lat, b_lat,
                     Wih_s, Whh_s, Wout_s, h_f32, h_seq, bar);
  hipLaunchKernelGGL(gitab_k, dim3(512), dim3(512), 0, stream, emb, Wih_s, gi_tab);

  void* kargs[] = {
    (void*)&Wout_s, (void*)&Whh_s, (void*)&gi_tab, (void*)&gh_buf, (void*)&h_f32,
    (void*)&h_seq, (void*)&candbufT, (void*)&b_ih, (void*)&b_hh, (void*)&b_out,
    (void*)&out, (void*)&bar
  };
  (void)hipLaunchCooperativeKernel((void*)decode_k, dim3(NBLK), dim3(512), kargs, 0, stream);
}